// Round 7
// baseline (909.840 us; speedup 1.0000x reference)
//
#include <hip/hip_runtime.h>
#include <math.h>

#define NTOK 110592      // B*D*H*W = 2*6*96*96
#define NWIN 864         // 2 * 3 * 12 * 12
#define TS   15925248    // NTOK*144

typedef unsigned short u16;
typedef unsigned int   u32;
typedef __attribute__((ext_vector_type(8))) short short8;
typedef __attribute__((ext_vector_type(4))) float float4v;

__device__ __forceinline__ float bf2f(u16 v) { return __uint_as_float(((u32)v) << 16); }
__device__ __forceinline__ u16 f2bf(float f) {
    u32 u = __float_as_uint(f);
    u32 r = u + 0x7fffu + ((u >> 16) & 1u);
    return (u16)(r >> 16);
}
__device__ __forceinline__ void unpack2(u32 u, float& lo, float& hi) {
    lo = __uint_as_float(u << 16);
    hi = __uint_as_float(u & 0xffff0000u);
}
__device__ __forceinline__ u32 pack2(float lo, float hi) {
    return (u32)f2bf(lo) | ((u32)f2bf(hi) << 16);
}
__device__ __forceinline__ float wave_sum(float v) {
    #pragma unroll
    for (int o = 32; o > 0; o >>= 1) v += __shfl_xor(v, o, 64);
    return v;
}

// windowed token index -> source spatial coords (handles roll for shifted layers)
__device__ __forceinline__ void win_to_src(int tw, int shifted, int& sb, int& sd, int& sh, int& sw) {
    int n = tw & 127;
    int win = tw >> 7;
    int ww = win % 12;
    int wh = (win / 12) % 12;
    int rest = win / 144;
    int wd = rest % 3;
    sb = rest / 3;
    int ld = n >> 6, lh = (n >> 3) & 7, lw = n & 7;
    int dr = wd * 2 + ld, hr = wh * 8 + lh, wr = ww * 8 + lw;
    if (shifted) {
        sd = (dr + 1) % 6;
        sh = (hr + 4) % 96;
        sw = (wr + 4) % 96;
    } else {
        sd = dr; sh = hr; sw = wr;
    }
}

// region id of window-local token t for the shifted-window mask
__device__ __forceinline__ int tok_region(int t, int wdn, int whn, int wwn) {
    int dr = wdn * 2 + (t >> 6), hr = whn * 8 + ((t >> 3) & 7), wr = wwn * 8 + (t & 7);
    int rd = (dr < 4) ? 0 : ((dr < 5) ? 1 : 2);
    int rh = (hr < 88) ? 0 : ((hr < 92) ? 1 : 2);
    int rw = (wr < 88) ? 0 : ((wr < 92) ? 1 : 2);
    return rd * 9 + rh * 3 + rw;
}

// ---------------- weight pre-conversion fp32 -> bf16 + bias-table expansion ----------------
// wbuf layout (u16 offsets): qkvw 0 (2x62208) | projw 124416 (2x20736) | fc1w 165888 (2x41472)
//                            | fc2w 248832 (2x41472) | linw 331776 (20736); total 352512
// bexp: [layer][head][128][128] f32 relative-position bias (196608 floats)
__global__ __launch_bounds__(256) void convert_weights(
    const float* __restrict__ qkvw, const float* __restrict__ projw,
    const float* __restrict__ fc1w, const float* __restrict__ fc2w,
    const float* __restrict__ linw, u16* __restrict__ wbuf,
    const float* __restrict__ rpb, float* __restrict__ bexp)
{
    int i = blockIdx.x * 256 + threadIdx.x;
    if (i < 124416) wbuf[i] = f2bf(qkvw[i]);
    else if (i < 165888) wbuf[i] = f2bf(projw[i - 124416]);
    else if (i < 248832) wbuf[i] = f2bf(fc1w[i - 165888]);
    else if (i < 331776) wbuf[i] = f2bf(fc2w[i - 248832]);
    else if (i < 352512) wbuf[i] = f2bf(linw[i - 331776]);
    else if (i < 549120) {
        int k = i - 352512;
        int n = k & 127, m = (k >> 7) & 127;
        int lh = k >> 14;
        int h = lh % 6, l = lh / 6;
        int rdi = (m >> 6) - (n >> 6) + 1;
        int rhi = ((m >> 3) & 7) - ((n >> 3) & 7) + 7;
        int rwi = (m & 7) - (n & 7) + 7;
        int bi = (rdi * 15 + rhi) * 15 + rwi;
        bexp[k] = rpb[l * 4050 + bi * 6 + h];
    }
}

// ---------------- conv3d(1x3x3) + bias + LN0, block = (b,d,h) row of 96 positions ----------------
// j-outer / position-inner: accumulators in VGPRs, weights+x-values register-cached.
__global__ __launch_bounds__(256) void conv_ln0_row(
    const float* __restrict__ x, const float* __restrict__ cw, const float* __restrict__ cb,
    const float* __restrict__ g0, const float* __restrict__ b0,
    float* __restrict__ y0)
{
    int bh = blockIdx.x;                 // (b*6+d)*96 + h
    int h = bh % 96, bd = bh / 96;
    int b = bd / 6, d = bd - b * 6;
    __shared__ float ws[192][29];        // conv weights, rows 144..191 zero; stride 29 -> conflict-free
    __shared__ float xsr[9][100];        // (ci*3+kh) x (w+pad)
    __shared__ float cbias[192], gg[144], bbv[144];
    int tid = threadIdx.x;

    for (int i = tid; i < 9 * 98; i += 256) {
        int row = i / 98, wx = i - row * 98;
        int ci = row / 3, kh = row - 3 * ci;
        int hh = h + kh - 1, wsrc = wx - 1;
        float v = 0.f;
        if (hh >= 0 && hh < 96 && wsrc >= 0 && wsrc < 96)
            v = x[((((size_t)b * 6 + d) * 3 + ci) * 96 + hh) * 96 + wsrc];
        xsr[row][wx] = v;
    }
    for (int i = tid; i < 192 * 27; i += 256) {
        int c = i / 27, j = i - c * 27;
        ws[c][j] = (c < 144) ? cw[c * 27 + j] : 0.f;
    }
    for (int i = tid; i < 192; i += 256) cbias[i] = (i < 144) ? cb[i] : 0.f;
    for (int i = tid; i < 144; i += 256) { gg[i] = g0[i]; bbv[i] = b0[i]; }
    __syncthreads();

    int wv = tid >> 6, lane = tid & 63;
    int p0 = wv * 24;                    // wave owns 24 contiguous positions

    float a0[24], a1[24], a2[24];
    #pragma unroll
    for (int k = 0; k < 24; k++) {
        a0[k] = cbias[lane]; a1[k] = cbias[lane + 64]; a2[k] = cbias[lane + 128];
    }

    for (int cikh = 0; cikh < 9; cikh++) {        // dynamic: keeps code small
        const float* xr = &xsr[cikh][p0];
        float xv[26];
        #pragma unroll
        for (int t = 0; t < 26; t++) xv[t] = xr[t];   // wave-uniform broadcasts
        #pragma unroll
        for (int kw = 0; kw < 3; kw++) {
            int j = cikh * 3 + kw;
            float w0 = ws[lane][j], w1 = ws[lane + 64][j], w2 = ws[lane + 128][j];
            #pragma unroll
            for (int k = 0; k < 24; k++) {
                float xvv = xv[k + kw];
                a0[k] += w0 * xvv; a1[k] += w1 * xvv; a2[k] += w2 * xvv;
            }
        }
    }

    #pragma unroll
    for (int k = 0; k < 24; k++) {
        int p = p0 + k;
        float v0 = a0[k], v1 = a1[k];
        float v2m = (lane < 16) ? a2[k] : 0.f;
        float s  = wave_sum(v0 + v1 + v2m);
        float s2 = wave_sum(v0 * v0 + v1 * v1 + v2m * v2m);
        float mu = s * (1.f / 144.f);
        float rstd = rsqrtf(fmaxf(s2 * (1.f / 144.f) - mu * mu, 0.f) + 1e-5f);
        size_t o = ((size_t)bh * 96 + p) * 144;
        float r0 = (v0 - mu) * rstd * gg[lane] + bbv[lane];
        float r1 = (v1 - mu) * rstd * gg[lane + 64] + bbv[lane + 64];
        y0[o + lane] = r0;
        y0[o + lane + 64] = r1;
        if (lane < 16) {
            float r2 = (a2[k] - mu) * rstd * gg[lane + 128] + bbv[lane + 128];
            y0[o + lane + 128] = r2;
        }
    }
}

// ---------------- LN per token -> bf16. MODE 0: identity; MODE 1: windowed gather; MODE 2: shifted ----------------
// float2 loads + packed u32 stores.
template<int MODE>
__global__ __launch_bounds__(256) void ln_gather(
    const float* __restrict__ in, u16* __restrict__ out,
    const float* __restrict__ g, const float* __restrict__ bt)
{
    int tok = blockIdx.x * 4 + (threadIdx.x >> 6);
    int lane = threadIdx.x & 63;
    int src;
    if (MODE == 0) src = tok;
    else {
        int b, d, h, w;
        win_to_src(tok, MODE == 2, b, d, h, w);
        src = ((b * 6 + d) * 96 + h) * 96 + w;
    }
    const float2* row = (const float2*)(in + (size_t)src * 144);
    float2 a = row[lane];
    float2 b2 = (lane < 8) ? row[64 + lane] : make_float2(0.f, 0.f);
    float s  = wave_sum(a.x + a.y + b2.x + b2.y);
    float s2 = wave_sum(a.x * a.x + a.y * a.y + b2.x * b2.x + b2.y * b2.y);
    float mu = s * (1.f / 144.f);
    float rstd = rsqrtf(fmaxf(s2 * (1.f / 144.f) - mu * mu, 0.f) + 1e-5f);
    const float2* g2 = (const float2*)g;
    const float2* t2 = (const float2*)bt;
    u32* orow = (u32*)(out + (size_t)tok * 144);
    float2 gg = g2[lane], tt = t2[lane];
    orow[lane] = pack2((a.x - mu) * rstd * gg.x + tt.x, (a.y - mu) * rstd * gg.y + tt.y);
    if (lane < 8) {
        float2 gh = g2[64 + lane], th = t2[64 + lane];
        orow[64 + lane] = pack2((b2.x - mu) * rstd * gh.x + th.x, (b2.y - mu) * rstd * gh.y + th.y);
    }
}

// ---------------- MFMA GEMM: C[M,N] = A[M,144*KTILES] @ W^T (+bias), tile 64x144, 192 thr ----------------
// A staged in LDS (vectorized 16B); B fragments read DIRECTLY from global (L1/L2-hot weights).
// AMODE: 0 fp32 A rows; 2 bf16 A rows. Wt is bf16 (pre-converted).
// EPI: 0 store bf16; 1 gelu->bf16; 2 scatter-add f32 (win_to_src); 3 add f32; 4 (y0+v)->bf16;
//      5 scatter f32 = y0[orow] + v (win_to_src);
//      6 qkv split store: Q,K (q pre-scaled) -> outb [head][tok][48]; V -> (u16*)fres as
//        transposed [head][win][24][128]. o_ld = rows/head (chunk tokens).
template<int AMODE, int EPI, int SHIFTED, int ADDBIAS, int KTILES>
__global__ __launch_bounds__(192) void mgemm(
    const void* __restrict__ Asrc, const u16* __restrict__ Wt, const float* __restrict__ bias,
    u16* __restrict__ outb, float* __restrict__ fres, const float* __restrict__ y0,
    int a_add, int a_ld, int w_ld, int o_ld, int o_add)
{
    __shared__ u16 As[64 * 152];
    int m0 = blockIdx.y * 64, n0 = blockIdx.x * 144;
    int tid = threadIdx.x;
    int wv3 = tid / 64, lane = tid & 63;
    int mrow = lane & 15, quad = lane >> 4;
    const short8 z8 = {0, 0, 0, 0, 0, 0, 0, 0};

    float4v acc[4][3];
    #pragma unroll
    for (int i = 0; i < 4; i++)
        #pragma unroll
        for (int j = 0; j < 3; j++) acc[i][j] = (float4v){0.f, 0.f, 0.f, 0.f};

    #pragma unroll
    for (int kt = 0; kt < KTILES; kt++) {
        if (kt) __syncthreads();
        // stage A (64 x 144 bf16), k-slice kt, 16B vector chunks
        if (AMODE == 2) {
            const u16* A = (const u16*)Asrc;
            #pragma unroll
            for (int idx = tid; idx < 1152; idx += 192) {   // 64 rows x 18 chunks
                int r = idx / 18, c4 = idx - r * 18;
                *(short8*)&As[r * 152 + c4 * 8] =
                    *(const short8*)&A[(size_t)(a_add + m0 + r) * a_ld + kt * 144 + c4 * 8];
            }
        } else {
            const float* A = (const float*)Asrc;
            #pragma unroll
            for (int idx = tid; idx < 2304; idx += 192) {   // 64 rows x 36 float4
                int r = idx / 36, c4 = idx - r * 36;
                const float4* src4 = (const float4*)&A[(size_t)(a_add + m0 + r) * a_ld + kt * 144];
                float4 v = src4[c4];
                *(u32*)&As[r * 152 + c4 * 4]     = pack2(v.x, v.y);
                *(u32*)&As[r * 152 + c4 * 4 + 2] = pack2(v.z, v.w);
            }
        }
        __syncthreads();

        const u16* Wg = Wt + (size_t)(n0 + wv3 * 48 + mrow) * w_ld + kt * 144;

        #pragma unroll
        for (int ks = 0; ks < 4; ks++) {
            int k0 = ks * 32;
            short8 af[4], bf[3];
            #pragma unroll
            for (int i = 0; i < 4; i++)
                af[i] = *(const short8*)&As[(i * 16 + mrow) * 152 + k0 + quad * 8];
            #pragma unroll
            for (int j = 0; j < 3; j++)
                bf[j] = *(const short8*)&Wg[(size_t)j * 16 * w_ld + k0 + quad * 8];
            #pragma unroll
            for (int i = 0; i < 4; i++)
                #pragma unroll
                for (int j = 0; j < 3; j++)
                    acc[i][j] = __builtin_amdgcn_mfma_f32_16x16x32_bf16(af[i], bf[j], acc[i][j], 0, 0, 0);
        }
        {   // K-tail 128..143: quads 2,3 supply zeros
            bool tl = (quad < 2);
            short8 af[4], bf[3];
            #pragma unroll
            for (int i = 0; i < 4; i++)
                af[i] = tl ? *(const short8*)&As[(i * 16 + mrow) * 152 + 128 + quad * 8] : z8;
            #pragma unroll
            for (int j = 0; j < 3; j++)
                bf[j] = tl ? *(const short8*)&Wg[(size_t)j * 16 * w_ld + 128 + quad * 8] : z8;
            #pragma unroll
            for (int i = 0; i < 4; i++)
                #pragma unroll
                for (int j = 0; j < 3; j++)
                    acc[i][j] = __builtin_amdgcn_mfma_f32_16x16x32_bf16(af[i], bf[j], acc[i][j], 0, 0, 0);
        }
    }

    // epilogue. C/D layout: col = lane&15 (n), row = quad*4 + reg (m)
    #pragma unroll
    for (int i = 0; i < 4; i++) {
        #pragma unroll
        for (int reg = 0; reg < 4; reg++) {
            int m = m0 + i * 16 + quad * 4 + reg;
            int orow;
            if (EPI == 2 || EPI == 5) {
                int b, d, h, w;
                win_to_src(m, SHIFTED, b, d, h, w);
                orow = ((b * 6 + d) * 96 + h) * 96 + w;
            } else orow = m + o_add;
            #pragma unroll
            for (int j = 0; j < 3; j++) {
                int n = n0 + wv3 * 48 + j * 16 + mrow;
                float v = acc[i][j][reg];
                if (ADDBIAS) v += bias[n];
                if (EPI == 1) v = 0.5f * v * (1.f + erff(v * 0.70710678118f));
                if (EPI == 2 || EPI == 3) {
                    fres[(size_t)orow * 144 + n] += v;
                } else if (EPI == 5) {
                    fres[(size_t)orow * 144 + n] = y0[(size_t)orow * 144 + n] + v;
                } else if (EPI == 6) {
                    int slot = n / 144;
                    int hn = n - slot * 144;
                    int head = hn / 24, dd = hn - head * 24;
                    if (slot == 0) {
                        v *= 0.20412414523193154f;  // q pre-scale
                        outb[((size_t)head * o_ld + orow) * 48 + dd] = f2bf(v);
                    } else if (slot == 1) {
                        outb[((size_t)head * o_ld + orow) * 48 + 24 + dd] = f2bf(v);
                    } else {
                        u16* vt = (u16*)fres;
                        vt[(((size_t)head * (o_ld >> 7) + (orow >> 7)) * 24 + dd) * 128
                           + (orow & 127)] = f2bf(v);
                    }
                } else {
                    if (EPI == 4) v += y0[(size_t)orow * o_ld + n];
                    outb[(size_t)orow * o_ld + n] = f2bf(v);
                }
            }
        }
    }
}

// ---------------- window attention via MFMA: block=(win,head), 4 waves, 32-query strip per wave ----------------
// qk [head][tok][48] (q pre-scaled), vt [head][win][24][128] (transposed at source, global b128 reads).
// Swapped QK^T -> in-lane softmax (no-max, bounded logits), cvt_pk bf16 P, per-wave LDS P strip only.
template<int SHIFTED>
__global__ __launch_bounds__(256) void attn_mfma(
    const u16* __restrict__ qk, const u16* __restrict__ vt,
    const float* __restrict__ bexp,     // layer's expanded bias [6][128][128]
    u16* __restrict__ tok_out, int win_base, int chtok)
{
    int win = blockIdx.x;
    int head = blockIdx.y;
    __shared__ __align__(16) u16 Pb[4][16][152];   // per-wave P strip (19.5 KB)
    __shared__ float invden_s[128];
    __shared__ u32 reg_pack[32];                   // 4 packed region bytes per entry

    int tid = threadIdx.x;
    int wv = tid >> 6, lane = tid & 63;
    int c = lane & 15, quad = lane >> 4;
    int qbase = wv * 32;
    const short8 z8 = {0, 0, 0, 0, 0, 0, 0, 0};
    const float* bh_ = bexp + head * 16384;
    const u16* base = qk + ((size_t)head * chtok + (size_t)win * 128) * 48;
    const u16* vtw  = vt + ((size_t)head * (chtok >> 7) + win) * 3072;

    int wdn = 0, whn = 0, wwn = 0;
    if (SHIFTED) {
        int wib = (win_base + win) % 432;
        wwn = wib % 12; whn = (wib / 12) % 12; wdn = wib / 144;
        if (tid < 32) {
            int t0 = tid * 4;
            reg_pack[tid] = (u32)tok_region(t0, wdn, whn, wwn)
                          | ((u32)tok_region(t0 + 1, wdn, whn, wwn) << 8)
                          | ((u32)tok_region(t0 + 2, wdn, whn, wwn) << 16)
                          | ((u32)tok_region(t0 + 3, wdn, whn, wwn) << 24);
        }
        __syncthreads();
    }

    // ---- Q fragments (B-operand): rows qbase + i*16 + c ----
    short8 aq[2];
    #pragma unroll
    for (int i = 0; i < 2; i++) {
        aq[i] = z8;
        if (quad < 3)
            aq[i] = *(const short8*)(base + (size_t)(qbase + i * 16 + c) * 48 + quad * 8);
    }

    // ---- S^T = K Q^T (swapped operands): lane holds S[q=i*16+c][k=j*16+quad*4+r] ----
    float4v s_acc[2][8];
    #pragma unroll
    for (int i = 0; i < 2; i++)
        #pragma unroll
        for (int j = 0; j < 8; j++) s_acc[i][j] = (float4v){0.f, 0.f, 0.f, 0.f};

    #pragma unroll
    for (int j = 0; j < 8; j++) {
        short8 kf = z8;
        if (quad < 3)
            kf = *(const short8*)(base + (size_t)(j * 16 + c) * 48 + 24 + quad * 8);
        s_acc[0][j] = __builtin_amdgcn_mfma_f32_16x16x32_bf16(kf, aq[0], s_acc[0][j], 0, 0, 0);
        s_acc[1][j] = __builtin_amdgcn_mfma_f32_16x16x32_bf16(kf, aq[1], s_acc[1][j], 0, 0, 0);
    }

    float4v o_acc[2][2];
    #pragma unroll
    for (int i = 0; i < 2; i++)
        #pragma unroll
        for (int jv = 0; jv < 2; jv++) o_acc[i][jv] = (float4v){0.f, 0.f, 0.f, 0.f};

    // ---- per 16-query half: no-max softmax (in-lane) -> P(bf16, LDS) -> PV MFMA (V^T from global) ----
    #pragma unroll
    for (int i = 0; i < 2; i++) {
        int m = qbase + i * 16 + c;
        const float* brow = bh_ + m * 128;
        u32 myreg = SHIFTED ? (u32)tok_region(m, wdn, whn, wwn) : 0u;
        float den = 0.f;
        #pragma unroll
        for (int j = 0; j < 8; j++) {
            float4 bv = *(const float4*)(brow + j * 16 + quad * 4);
            float s0 = s_acc[i][j][0] + bv.x;
            float s1 = s_acc[i][j][1] + bv.y;
            float s2 = s_acc[i][j][2] + bv.z;
            float s3 = s_acc[i][j][3] + bv.w;
            if (SHIFTED) {
                u32 rv = reg_pack[j * 4 + quad];
                s0 += ((rv & 255u) == myreg) ? 0.f : -100.f;
                s1 += (((rv >> 8) & 255u) == myreg) ? 0.f : -100.f;
                s2 += (((rv >> 16) & 255u) == myreg) ? 0.f : -100.f;
                s3 += ((rv >> 24) == myreg) ? 0.f : -100.f;
            }
            float p0 = __expf(s0), p1 = __expf(s1), p2 = __expf(s2), p3 = __expf(s3);
            den += (p0 + p1) + (p2 + p3);
            u32 w0, w1;
            asm("v_cvt_pk_bf16_f32 %0, %1, %2" : "=v"(w0) : "v"(p0), "v"(p1));
            asm("v_cvt_pk_bf16_f32 %0, %1, %2" : "=v"(w1) : "v"(p2), "v"(p3));
            uint2 wpair = make_uint2(w0, w1);
            *(uint2*)&Pb[wv][c][j * 16 + quad * 4] = wpair;
        }
        den += __shfl_xor(den, 16, 64);
        den += __shfl_xor(den, 32, 64);
        if (quad == 0) invden_s[m] = 1.f / den;

        #pragma unroll
        for (int ks = 0; ks < 4; ks++) {
            short8 pf  = *(const short8*)&Pb[wv][c][ks * 32 + quad * 8];
            short8 vf0 = *(const short8*)&vtw[c * 128 + ks * 32 + quad * 8];
            short8 vf1 = (c < 8) ? *(const short8*)&vtw[(16 + c) * 128 + ks * 32 + quad * 8] : z8;
            o_acc[i][0] = __builtin_amdgcn_mfma_f32_16x16x32_bf16(pf, vf0, o_acc[i][0], 0, 0, 0);
            o_acc[i][1] = __builtin_amdgcn_mfma_f32_16x16x32_bf16(pf, vf1, o_acc[i][1], 0, 0, 0);
        }
    }

    // ---- park O (f32) in the wave's P region for coalesced write-out ----
    float* ob = (float*)&Pb[wv][0][0];             // [32][26] f32 = 3328 B <= 4864 B
    #pragma unroll
    for (int i = 0; i < 2; i++)
        #pragma unroll
        for (int jv = 0; jv < 2; jv++) {
            int d = jv * 16 + c;
            if (d < 24) {
                #pragma unroll
                for (int r = 0; r < 4; r++)
                    ob[(i * 16 + quad * 4 + r) * 26 + d] = o_acc[i][jv][r];
            }
        }
    __syncthreads();

    if (tid < 128) {
        const float2* ol = (const float2*)((const float*)&Pb[0][0][0]
                                           + (tid >> 5) * 1216 + (tid & 31) * 26);
        float inv = invden_s[tid];
        u32* orow = (u32*)tok_out + ((size_t)((win_base + win) * 128 + tid)) * 72 + head * 12;
        #pragma unroll
        for (int d2 = 0; d2 < 12; d2++) {
            float2 v = ol[d2];
            orow[d2] = pack2(v.x * inv, v.y * inv);
        }
    }
}

// ---------------- final LN + transpose to (b, d, c, h, w), f32 out ----------------
__global__ __launch_bounds__(256) void final_ln_out_kernel(
    const u16* __restrict__ gsrc, const float* __restrict__ g, const float* __restrict__ bt,
    float* __restrict__ out)
{
    int bh = blockIdx.x;
    int h = bh % 96, d = (bh / 96) % 6, b = bh / 576;
    __shared__ u16 tile[96][152];      // bf16 tile: 29.2 KB -> 5 blocks/CU
    __shared__ float stat[96][2];
    const u16* src = gsrc + (size_t)bh * 96 * 144;
    for (int i = threadIdx.x; i < 1728; i += 256) {       // 96 rows x 18 short8
        int wt = i / 18, c8 = i - wt * 18;
        *(short8*)&tile[wt][c8 * 8] = *(const short8*)&src[wt * 144 + c8 * 8];
    }
    __syncthreads();
    if (threadIdx.x < 96) {
        const u32* row = (const u32*)&tile[threadIdx.x][0];
        float s = 0.f, s2 = 0.f;
        #pragma unroll
        for (int j = 0; j < 72; j++) {
            float lo, hi; unpack2(row[j], lo, hi);
            s += lo + hi; s2 += lo * lo + hi * hi;
        }
        float mu = s * (1.f / 144.f);
        float var = s2 * (1.f / 144.f) - mu * mu;
        stat[threadIdx.x][0] = mu;
        stat[threadIdx.x][1] = rsqrtf(fmaxf(var, 0.f) + 1e-5f);
    }
    __syncthreads();
    size_t obase = ((size_t)(b * 6 + d) * 144) * 9216 + h * 96;
    for (int i = threadIdx.x; i < 96 * 144; i += blockDim.x) {
        int c = i / 96, wt = i - c * 96;
        out[obase + (size_t)c * 9216 + wt] =
            (bf2f(tile[wt][c]) - stat[wt][0]) * stat[wt][1] * g[c] + bt[c];
    }
}

extern "C" void kernel_launch(void* const* d_in, const int* in_sizes, int n_in,
                              void* d_out, int out_size, void* d_ws, size_t ws_size,
                              hipStream_t stream) {
    const float* x     = (const float*)d_in[0];
    const float* convw = (const float*)d_in[1];
    const float* convb = (const float*)d_in[2];
    const float* ln0g  = (const float*)d_in[3];
    const float* ln0b  = (const float*)d_in[4];
    const float* n1g   = (const float*)d_in[5];
    const float* n1b   = (const float*)d_in[6];
    const float* qkvw  = (const float*)d_in[7];
    const float* qkvb  = (const float*)d_in[8];
    const float* rpb   = (const float*)d_in[9];
    const float* projw = (const float*)d_in[10];
    const float* projb = (const float*)d_in[11];
    const float* n2g   = (const float*)d_in[12];
    const float* n2b   = (const float*)d_in[13];
    const float* fc1w  = (const float*)d_in[14];
    const float* fc1b  = (const float*)d_in[15];
    const float* fc2w  = (const float*)d_in[16];
    const float* fc2b  = (const float*)d_in[17];
    const float* linw  = (const float*)d_in[18];
    const float* linb  = (const float*)d_in[19];
    const float* ln1g  = (const float*)d_in[20];
    const float* ln1b  = (const float*)d_in[21];

    // ws layout: f fp32 | tok bf16 | wbuf | bexp | qkvbuf (rest; sized by ws_size)
    char* wp = (char*)d_ws;
    float* f    = (float*)wp;             wp += (size_t)TS * 4;
    u16*   tok  = (u16*)wp;               wp += (size_t)TS * 2;
    u16*   wbuf = (u16*)wp;               wp += 352512ull * 2;
    float* bexp = (float*)wp;             wp += 196608ull * 4;
    u16*   qkvbuf = (u16*)wp;
    size_t rest = ws_size - (size_t)(wp - (char*)d_ws);
    // attention chunk count: qk+vt buffers total NTOK*432 bf16 / nch
    int nch = (rest >= (size_t)NTOK * 432 * 2) ? 1
            : (rest >= (size_t)NTOK * 216 * 2) ? 2 : 4;
    // MLP chunk count: hidden buffer is NTOK*288 bf16 / nm
    int nm  = (rest >= (size_t)NTOK * 288 * 2) ? 1
            : (rest >= (size_t)NTOK * 144 * 2) ? 2 : 3;
    float* y0 = (float*)d_out;   // conv+LN0 output parked in d_out until the end

    convert_weights<<<2145, 256, 0, stream>>>(qkvw, projw, fc1w, fc2w, linw, wbuf, rpb, bexp);
    conv_ln0_row<<<1152, 256, 0, stream>>>(x, convw, convb, ln0g, ln0b, y0);

    for (int layer = 0; layer < 2; ++layer) {
        const u16* qw  = wbuf + (size_t)layer * 62208;
        const u16* pw  = wbuf + 124416 + (size_t)layer * 20736;
        const u16* f1w = wbuf + 165888 + (size_t)layer * 41472;
        const u16* f2w = wbuf + 248832 + (size_t)layer * 41472;
        const float* qb  = qkvb + (size_t)layer * 432;
        const float* pb  = projb + (size_t)layer * 144;
        const float* g1  = n1g + layer * 144;
        const float* b1  = n1b + layer * 144;
        const float* g2  = n2g + layer * 144;
        const float* b2  = n2b + layer * 144;
        const float* f1b = fc1b + (size_t)layer * 288;
        const float* f2b = fc2b + (size_t)layer * 144;
        const float* bx  = bexp + (size_t)layer * 98304;

        // LN1 + roll + window partition -> tok (windowed bf16 rows)
        // layer 0 reads conv+LN0 output (y0); layer 1 reads the residual stream f
        if (layer == 0) ln_gather<1><<<NTOK / 4, 256, 0, stream>>>(y0, tok, g1, b1);
        else            ln_gather<2><<<NTOK / 4, 256, 0, stream>>>(f, tok, g1, b1);

        // attention in nch token chunks; attn output overwrites tok rows of its chunk
        int chtok = NTOK / nch, chwin = NWIN / nch;
        u16* vtb = qkvbuf + (size_t)288 * chtok;   // V^T region after QK region
        for (int c = 0; c < nch; c++) {
            mgemm<2, 6, 0, 1, 1><<<dim3(3, chtok / 64), 192, 0, stream>>>(
                tok, qw, qb, qkvbuf, (float*)vtb, nullptr,
                c * chtok, 144, 144, chtok, 0);
            if (layer == 0)
                attn_mfma<0><<<dim3(chwin, 6), 256, 0, stream>>>(qkvbuf, vtb, bx, tok, c * chwin, chtok);
            else
                attn_mfma<1><<<dim3(chwin, 6), 256, 0, stream>>>(qkvbuf, vtb, bx, tok, c * chwin, chtok);
        }

        // proj + window-reverse scatter into f
        // layer 0: f = y0 + proj (f not yet initialized); layer 1: f += proj
        if (layer == 0)
            mgemm<2, 5, 0, 1, 1><<<dim3(1, NTOK / 64), 192, 0, stream>>>(
                tok, pw, pb, nullptr, f, y0, 0, 144, 144, 144, 0);
        else
            mgemm<2, 2, 1, 1, 1><<<dim3(1, NTOK / 64), 192, 0, stream>>>(
                tok, pw, pb, nullptr, f, nullptr, 0, 144, 144, 144, 0);

        // LN2 (identity order) -> tok
        ln_gather<0><<<NTOK / 4, 256, 0, stream>>>(f, tok, g2, b2);

        // MLP in nm chunks (hidden lives in qkvbuf: fcch x 288 bf16)
        int fcch = NTOK / nm;
        for (int c = 0; c < nm; c++) {
            int mst = c * fcch;
            mgemm<2, 1, 0, 1, 1><<<dim3(2, fcch / 64), 192, 0, stream>>>(
                tok, f1w, f1b, qkvbuf, nullptr, nullptr, mst, 144, 144, 288, 0);
            mgemm<2, 3, 0, 1, 2><<<dim3(1, fcch / 64), 192, 0, stream>>>(
                qkvbuf, f2w, f2b, nullptr, f, nullptr, 0, 288, 288, 144, mst);
        }
    }

    // final linear + conv-residual y0 -> tok (bf16, spatial rows)
    mgemm<0, 4, 0, 1, 1><<<dim3(1, NTOK / 64), 192, 0, stream>>>(
        f, wbuf + 331776, linb, tok, nullptr, y0, 0, 144, 144, 144, 0);

    // trailing LN + transpose to (n, d, c, h, w), fp32 out
    final_ln_out_kernel<<<2 * 6 * 96, 256, 0, stream>>>(tok, ln1g, ln1b, (float*)d_out);
}

// Round 8
// 852.606 us; speedup vs baseline: 1.0671x; 1.0671x over previous
//
#include <hip/hip_runtime.h>
#include <math.h>

#define NTOK 110592      // B*D*H*W = 2*6*96*96
#define NWIN 864         // 2 * 3 * 12 * 12
#define TS   15925248    // NTOK*144

typedef unsigned short u16;
typedef unsigned int   u32;
typedef __attribute__((ext_vector_type(8))) short short8;
typedef __attribute__((ext_vector_type(4))) float float4v;

__device__ __forceinline__ float bf2f(u16 v) { return __uint_as_float(((u32)v) << 16); }
__device__ __forceinline__ u16 f2bf(float f) {
    u32 u = __float_as_uint(f);
    u32 r = u + 0x7fffu + ((u >> 16) & 1u);
    return (u16)(r >> 16);
}
__device__ __forceinline__ void unpack2(u32 u, float& lo, float& hi) {
    lo = __uint_as_float(u << 16);
    hi = __uint_as_float(u & 0xffff0000u);
}
__device__ __forceinline__ u32 pack2(float lo, float hi) {
    return (u32)f2bf(lo) | ((u32)f2bf(hi) << 16);
}
__device__ __forceinline__ float wave_sum(float v) {
    #pragma unroll
    for (int o = 32; o > 0; o >>= 1) v += __shfl_xor(v, o, 64);
    return v;
}

// windowed token index -> source spatial coords (handles roll for shifted layers)
__device__ __forceinline__ void win_to_src(int tw, int shifted, int& sb, int& sd, int& sh, int& sw) {
    int n = tw & 127;
    int win = tw >> 7;
    int ww = win % 12;
    int wh = (win / 12) % 12;
    int rest = win / 144;
    int wd = rest % 3;
    sb = rest / 3;
    int ld = n >> 6, lh = (n >> 3) & 7, lw = n & 7;
    int dr = wd * 2 + ld, hr = wh * 8 + lh, wr = ww * 8 + lw;
    if (shifted) {
        sd = (dr + 1) % 6;
        sh = (hr + 4) % 96;
        sw = (wr + 4) % 96;
    } else {
        sd = dr; sh = hr; sw = wr;
    }
}

// region id of window-local token t for the shifted-window mask
__device__ __forceinline__ int tok_region(int t, int wdn, int whn, int wwn) {
    int dr = wdn * 2 + (t >> 6), hr = whn * 8 + ((t >> 3) & 7), wr = wwn * 8 + (t & 7);
    int rd = (dr < 4) ? 0 : ((dr < 5) ? 1 : 2);
    int rh = (hr < 88) ? 0 : ((hr < 92) ? 1 : 2);
    int rw = (wr < 88) ? 0 : ((wr < 92) ? 1 : 2);
    return rd * 9 + rh * 3 + rw;
}

// ---------------- weight pre-conversion fp32 -> bf16 + bias-table expansion ----------------
// wbuf layout (u16 offsets): qkvw 0 (2x62208) | projw 124416 (2x20736) | fc1w 165888 (2x41472)
//                            | fc2w 248832 (2x41472) | linw 331776 (20736); total 352512
// bexp: [layer][head][128][128] f32 relative-position bias (196608 floats)
__global__ __launch_bounds__(256) void convert_weights(
    const float* __restrict__ qkvw, const float* __restrict__ projw,
    const float* __restrict__ fc1w, const float* __restrict__ fc2w,
    const float* __restrict__ linw, u16* __restrict__ wbuf,
    const float* __restrict__ rpb, float* __restrict__ bexp)
{
    int i = blockIdx.x * 256 + threadIdx.x;
    if (i < 124416) wbuf[i] = f2bf(qkvw[i]);
    else if (i < 165888) wbuf[i] = f2bf(projw[i - 124416]);
    else if (i < 248832) wbuf[i] = f2bf(fc1w[i - 165888]);
    else if (i < 331776) wbuf[i] = f2bf(fc2w[i - 248832]);
    else if (i < 352512) wbuf[i] = f2bf(linw[i - 331776]);
    else if (i < 549120) {
        int k = i - 352512;
        int n = k & 127, m = (k >> 7) & 127;
        int lh = k >> 14;
        int h = lh % 6, l = lh / 6;
        int rdi = (m >> 6) - (n >> 6) + 1;
        int rhi = ((m >> 3) & 7) - ((n >> 3) & 7) + 7;
        int rwi = (m & 7) - (n & 7) + 7;
        int bi = (rdi * 15 + rhi) * 15 + rwi;
        bexp[k] = rpb[l * 4050 + bi * 6 + h];
    }
}

// ---------------- conv3d(1x3x3) + bias + LN0, block = (b,d,h) row of 96 positions ----------------
__global__ __launch_bounds__(256) void conv_ln0_row(
    const float* __restrict__ x, const float* __restrict__ cw, const float* __restrict__ cb,
    const float* __restrict__ g0, const float* __restrict__ b0,
    float* __restrict__ y0)
{
    int bh = blockIdx.x;                 // (b*6+d)*96 + h
    int h = bh % 96, bd = bh / 96;
    int b = bd / 6, d = bd - b * 6;
    __shared__ float ws[192][29];        // conv weights, rows 144..191 zero; stride 29 -> conflict-free
    __shared__ float xsr[9][100];        // (ci*3+kh) x (w+pad)
    __shared__ float cbias[192], gg[144], bbv[144];
    int tid = threadIdx.x;

    for (int i = tid; i < 9 * 98; i += 256) {
        int row = i / 98, wx = i - row * 98;
        int ci = row / 3, kh = row - 3 * ci;
        int hh = h + kh - 1, wsrc = wx - 1;
        float v = 0.f;
        if (hh >= 0 && hh < 96 && wsrc >= 0 && wsrc < 96)
            v = x[((((size_t)b * 6 + d) * 3 + ci) * 96 + hh) * 96 + wsrc];
        xsr[row][wx] = v;
    }
    for (int i = tid; i < 192 * 27; i += 256) {
        int c = i / 27, j = i - c * 27;
        ws[c][j] = (c < 144) ? cw[c * 27 + j] : 0.f;
    }
    for (int i = tid; i < 192; i += 256) cbias[i] = (i < 144) ? cb[i] : 0.f;
    for (int i = tid; i < 144; i += 256) { gg[i] = g0[i]; bbv[i] = b0[i]; }
    __syncthreads();

    int wv = tid >> 6, lane = tid & 63;
    int p0 = wv * 24;                    // wave owns 24 contiguous positions

    float a0[24], a1[24], a2[24];
    #pragma unroll
    for (int k = 0; k < 24; k++) {
        a0[k] = cbias[lane]; a1[k] = cbias[lane + 64]; a2[k] = cbias[lane + 128];
    }

    for (int cikh = 0; cikh < 9; cikh++) {
        const float* xr = &xsr[cikh][p0];
        float xv[26];
        #pragma unroll
        for (int t = 0; t < 26; t++) xv[t] = xr[t];   // wave-uniform broadcasts
        #pragma unroll
        for (int kw = 0; kw < 3; kw++) {
            int j = cikh * 3 + kw;
            float w0 = ws[lane][j], w1 = ws[lane + 64][j], w2 = ws[lane + 128][j];
            #pragma unroll
            for (int k = 0; k < 24; k++) {
                float xvv = xv[k + kw];
                a0[k] += w0 * xvv; a1[k] += w1 * xvv; a2[k] += w2 * xvv;
            }
        }
    }

    #pragma unroll
    for (int k = 0; k < 24; k++) {
        int p = p0 + k;
        float v0 = a0[k], v1 = a1[k];
        float v2m = (lane < 16) ? a2[k] : 0.f;
        float s  = wave_sum(v0 + v1 + v2m);
        float s2 = wave_sum(v0 * v0 + v1 * v1 + v2m * v2m);
        float mu = s * (1.f / 144.f);
        float rstd = rsqrtf(fmaxf(s2 * (1.f / 144.f) - mu * mu, 0.f) + 1e-5f);
        size_t o = ((size_t)bh * 96 + p) * 144;
        float r0 = (v0 - mu) * rstd * gg[lane] + bbv[lane];
        float r1 = (v1 - mu) * rstd * gg[lane + 64] + bbv[lane + 64];
        y0[o + lane] = r0;
        y0[o + lane + 64] = r1;
        if (lane < 16) {
            float r2 = (a2[k] - mu) * rstd * gg[lane + 128] + bbv[lane + 128];
            y0[o + lane + 128] = r2;
        }
    }
}

// ---------------- LN per token -> bf16. MODE 0: identity; MODE 1: windowed gather; MODE 2: shifted ----------------
// float2 loads + packed u32 stores.
template<int MODE>
__global__ __launch_bounds__(256) void ln_gather(
    const float* __restrict__ in, u16* __restrict__ out,
    const float* __restrict__ g, const float* __restrict__ bt)
{
    int tok = blockIdx.x * 4 + (threadIdx.x >> 6);
    int lane = threadIdx.x & 63;
    int src;
    if (MODE == 0) src = tok;
    else {
        int b, d, h, w;
        win_to_src(tok, MODE == 2, b, d, h, w);
        src = ((b * 6 + d) * 96 + h) * 96 + w;
    }
    const float2* row = (const float2*)(in + (size_t)src * 144);
    float2 a = row[lane];
    float2 b2 = (lane < 8) ? row[64 + lane] : make_float2(0.f, 0.f);
    float s  = wave_sum(a.x + a.y + b2.x + b2.y);
    float s2 = wave_sum(a.x * a.x + a.y * a.y + b2.x * b2.x + b2.y * b2.y);
    float mu = s * (1.f / 144.f);
    float rstd = rsqrtf(fmaxf(s2 * (1.f / 144.f) - mu * mu, 0.f) + 1e-5f);
    const float2* g2 = (const float2*)g;
    const float2* t2 = (const float2*)bt;
    u32* orow = (u32*)(out + (size_t)tok * 144);
    float2 gg = g2[lane], tt = t2[lane];
    orow[lane] = pack2((a.x - mu) * rstd * gg.x + tt.x, (a.y - mu) * rstd * gg.y + tt.y);
    if (lane < 8) {
        float2 gh = g2[64 + lane], th = t2[64 + lane];
        orow[64 + lane] = pack2((b2.x - mu) * rstd * gh.x + th.x, (b2.y - mu) * rstd * gh.y + th.y);
    }
}

// ---------------- MFMA GEMM: C[M, NB*144] = A[M,144*KTILES] @ W^T (+bias), tile 64 rows, 192 thr ----------------
// A staged ONCE in LDS and reused across NB column sub-tiles (grid.x == 1 always).
// B fragments read DIRECTLY from global (L1/L2-hot weights).
// AMODE: 0 fp32 A rows; 2 bf16 A rows. Wt is bf16 (pre-converted).
// EPI: 0 store bf16; 1 gelu->bf16; 2 scatter-add f32 (win_to_src); 3 add f32; 4 (y0+v)->bf16;
//      5 scatter f32 = y0[orow] + v (win_to_src);
//      6 head-major qkv store: out[((head*o_ld)+orow)*72 + slot*24 + d], q pre-scaled (o_ld = rows/head).
// NB>1 requires KTILES==1.
template<int AMODE, int EPI, int SHIFTED, int ADDBIAS, int KTILES, int NB>
__global__ __launch_bounds__(192) void mgemm(
    const void* __restrict__ Asrc, const u16* __restrict__ Wt, const float* __restrict__ bias,
    u16* __restrict__ outb, float* __restrict__ fres, const float* __restrict__ y0,
    int a_add, int a_ld, int w_ld, int o_ld, int o_add)
{
    __shared__ u16 As[64 * 152];
    int m0 = blockIdx.y * 64;
    int tid = threadIdx.x;
    int wv3 = tid / 64, lane = tid & 63;
    int mrow = lane & 15, quad = lane >> 4;
    const short8 z8 = {0, 0, 0, 0, 0, 0, 0, 0};

    float4v acc[4][3];

    auto zero_acc = [&]() {
        #pragma unroll
        for (int i = 0; i < 4; i++)
            #pragma unroll
            for (int j = 0; j < 3; j++) acc[i][j] = (float4v){0.f, 0.f, 0.f, 0.f};
    };

    auto stageA = [&](int kt) {
        if (AMODE == 2) {
            const u16* A = (const u16*)Asrc;
            for (int idx = tid; idx < 1152; idx += 192) {   // 64 rows x 18 chunks
                int r = idx / 18, c4 = idx - r * 18;
                *(short8*)&As[r * 152 + c4 * 8] =
                    *(const short8*)&A[(size_t)(a_add + m0 + r) * a_ld + kt * 144 + c4 * 8];
            }
        } else {
            const float* A = (const float*)Asrc;
            for (int idx = tid; idx < 2304; idx += 192) {   // 64 rows x 36 float4
                int r = idx / 36, c4 = idx - r * 36;
                const float4* src4 = (const float4*)&A[(size_t)(a_add + m0 + r) * a_ld + kt * 144];
                float4 v = src4[c4];
                *(u32*)&As[r * 152 + c4 * 4]     = pack2(v.x, v.y);
                *(u32*)&As[r * 152 + c4 * 4 + 2] = pack2(v.z, v.w);
            }
        }
    };

    auto mfma_tile = [&](int n0, int kt) {
        const u16* Wg = Wt + (size_t)(n0 + wv3 * 48 + mrow) * w_ld + kt * 144;
        #pragma unroll
        for (int ks = 0; ks < 4; ks++) {
            int k0 = ks * 32;
            short8 af[4], bf[3];
            #pragma unroll
            for (int i = 0; i < 4; i++)
                af[i] = *(const short8*)&As[(i * 16 + mrow) * 152 + k0 + quad * 8];
            #pragma unroll
            for (int j = 0; j < 3; j++)
                bf[j] = *(const short8*)&Wg[(size_t)j * 16 * w_ld + k0 + quad * 8];
            #pragma unroll
            for (int i = 0; i < 4; i++)
                #pragma unroll
                for (int j = 0; j < 3; j++)
                    acc[i][j] = __builtin_amdgcn_mfma_f32_16x16x32_bf16(af[i], bf[j], acc[i][j], 0, 0, 0);
        }
        {   // K-tail 128..143: quads 2,3 supply zeros
            bool tl = (quad < 2);
            short8 af[4], bf[3];
            #pragma unroll
            for (int i = 0; i < 4; i++)
                af[i] = tl ? *(const short8*)&As[(i * 16 + mrow) * 152 + 128 + quad * 8] : z8;
            #pragma unroll
            for (int j = 0; j < 3; j++)
                bf[j] = tl ? *(const short8*)&Wg[(size_t)j * 16 * w_ld + 128 + quad * 8] : z8;
            #pragma unroll
            for (int i = 0; i < 4; i++)
                #pragma unroll
                for (int j = 0; j < 3; j++)
                    acc[i][j] = __builtin_amdgcn_mfma_f32_16x16x32_bf16(af[i], bf[j], acc[i][j], 0, 0, 0);
        }
    };

    auto epilogue = [&](int n0) {
        // C/D layout: col = lane&15 (n), row = quad*4 + reg (m)
        #pragma unroll
        for (int i = 0; i < 4; i++) {
            #pragma unroll
            for (int reg = 0; reg < 4; reg++) {
                int m = m0 + i * 16 + quad * 4 + reg;
                int orow;
                if (EPI == 2 || EPI == 5) {
                    int b, d, h, w;
                    win_to_src(m, SHIFTED, b, d, h, w);
                    orow = ((b * 6 + d) * 96 + h) * 96 + w;
                } else orow = m + o_add;
                #pragma unroll
                for (int j = 0; j < 3; j++) {
                    int n = n0 + wv3 * 48 + j * 16 + mrow;
                    float v = acc[i][j][reg];
                    if (ADDBIAS) v += bias[n];
                    if (EPI == 1) v = 0.5f * v * (1.f + erff(v * 0.70710678118f));
                    if (EPI == 2 || EPI == 3) {
                        fres[(size_t)orow * 144 + n] += v;
                    } else if (EPI == 5) {
                        fres[(size_t)orow * 144 + n] = y0[(size_t)orow * 144 + n] + v;
                    } else if (EPI == 6) {
                        int slot = n / 144;
                        int hn = n - slot * 144;
                        int head = hn / 24, dd = hn - head * 24;
                        if (slot == 0) v *= 0.20412414523193154f;  // q pre-scale
                        outb[((size_t)head * o_ld + orow) * 72 + slot * 24 + dd] = f2bf(v);
                    } else {
                        if (EPI == 4) v += y0[(size_t)orow * o_ld + n];
                        outb[(size_t)orow * o_ld + n] = f2bf(v);
                    }
                }
            }
        }
    };

    if (NB == 1) {
        zero_acc();
        #pragma unroll
        for (int kt = 0; kt < KTILES; kt++) {
            if (kt) __syncthreads();
            stageA(kt);
            __syncthreads();
            mfma_tile(0, kt);
        }
        epilogue(0);
    } else {
        stageA(0);
        __syncthreads();
        #pragma unroll
        for (int nb = 0; nb < NB; nb++) {
            zero_acc();
            mfma_tile(nb * 144, 0);
            epilogue(nb * 144);
        }
    }
}

// ---------------- window attention via MFMA: block=(win,head), 4 waves, 32-query strip per wave ----------------
// qkv head-major [head][tok][72] (q24|k24|v24, q pre-scaled). Swapped QK^T -> in-lane softmax
// (no-max, bounded logits), cvt_pk bf16 P. Vt and Pb use stride-128 rows with XOR swizzle
// idx ^= (row&7)<<3 on BOTH write and read sides -> ~2-way max bank aliasing.
template<int SHIFTED>
__global__ __launch_bounds__(256) void attn_mfma(
    const u16* __restrict__ qkv,        // chunk-local, head-major
    const float* __restrict__ bexp,     // layer's expanded bias [6][128][128]
    u16* __restrict__ tok_out, int win_base, int chtok)
{
    int win = blockIdx.x;
    int head = blockIdx.y;
    __shared__ __align__(16) u16 Pb[4][2048];      // per-wave P strip [16 rows][128], swizzled
    __shared__ __align__(16) u16 Vt[3072];         // V transposed [24 d-rows][128 tok], swizzled
    __shared__ float invden_s[128];
    __shared__ u32 reg_pack[32];                   // 4 packed region bytes per entry

    int tid = threadIdx.x;
    int wv = tid >> 6, lane = tid & 63;
    int c = lane & 15, quad = lane >> 4;
    int qbase = wv * 32;
    const short8 z8 = {0, 0, 0, 0, 0, 0, 0, 0};
    const float* bh_ = bexp + head * 16384;
    const u16* base = qkv + ((size_t)head * chtok + (size_t)win * 128) * 72;
    int cs = (c & 7) << 3;                          // this lane's row-swizzle (rows c and 16+c)

    int wdn = 0, whn = 0, wwn = 0;
    if (SHIFTED) {
        int wib = (win_base + win) % 432;
        wwn = wib % 12; whn = (wib / 12) % 12; wdn = wib / 144;
    }

    // ---- stage V transposed + swizzled, packed mask regions ----
    if (tid < 128) {
        const u32* vsrc = (const u32*)(base + (size_t)tid * 72 + 48);
        #pragma unroll
        for (int i = 0; i < 12; i++) {
            u32 u = vsrc[i];
            int d0 = 2 * i, d1 = 2 * i + 1;
            Vt[((d0 << 7) + tid) ^ ((d0 & 7) << 3)] = (u16)(u & 0xffffu);
            Vt[((d1 << 7) + tid) ^ ((d1 & 7) << 3)] = (u16)(u >> 16);
        }
    }
    if (SHIFTED && tid < 32) {
        int t0 = tid * 4;
        reg_pack[tid] = (u32)tok_region(t0, wdn, whn, wwn)
                      | ((u32)tok_region(t0 + 1, wdn, whn, wwn) << 8)
                      | ((u32)tok_region(t0 + 2, wdn, whn, wwn) << 16)
                      | ((u32)tok_region(t0 + 3, wdn, whn, wwn) << 24);
    }
    __syncthreads();

    // ---- Q fragments (B-operand): rows qbase + i*16 + c ----
    short8 aq[2];
    #pragma unroll
    for (int i = 0; i < 2; i++) {
        aq[i] = z8;
        if (quad < 3)
            aq[i] = *(const short8*)(base + (size_t)(qbase + i * 16 + c) * 72 + quad * 8);
    }

    // ---- S^T = K Q^T (swapped operands): lane holds S[q=i*16+c][k=j*16+quad*4+r] ----
    float4v s_acc[2][8];
    #pragma unroll
    for (int i = 0; i < 2; i++)
        #pragma unroll
        for (int j = 0; j < 8; j++) s_acc[i][j] = (float4v){0.f, 0.f, 0.f, 0.f};

    #pragma unroll
    for (int j = 0; j < 8; j++) {
        short8 kf = z8;
        if (quad < 3)
            kf = *(const short8*)(base + (size_t)(j * 16 + c) * 72 + 24 + quad * 8);
        s_acc[0][j] = __builtin_amdgcn_mfma_f32_16x16x32_bf16(kf, aq[0], s_acc[0][j], 0, 0, 0);
        s_acc[1][j] = __builtin_amdgcn_mfma_f32_16x16x32_bf16(kf, aq[1], s_acc[1][j], 0, 0, 0);
    }

    float4v o_acc[2][2];
    #pragma unroll
    for (int i = 0; i < 2; i++)
        #pragma unroll
        for (int jv = 0; jv < 2; jv++) o_acc[i][jv] = (float4v){0.f, 0.f, 0.f, 0.f};

    // ---- per 16-query half: no-max softmax (in-lane) -> P(bf16, swizzled LDS) -> PV MFMA ----
    #pragma unroll
    for (int i = 0; i < 2; i++) {
        int m = qbase + i * 16 + c;
        const float* brow = bh_ + m * 128;
        u32 myreg = SHIFTED ? (u32)tok_region(m, wdn, whn, wwn) : 0u;
        float den = 0.f;
        #pragma unroll
        for (int j = 0; j < 8; j++) {
            float4 bv = *(const float4*)(brow + j * 16 + quad * 4);
            float s0 = s_acc[i][j][0] + bv.x;
            float s1 = s_acc[i][j][1] + bv.y;
            float s2 = s_acc[i][j][2] + bv.z;
            float s3 = s_acc[i][j][3] + bv.w;
            if (SHIFTED) {
                u32 rv = reg_pack[j * 4 + quad];
                s0 += ((rv & 255u) == myreg) ? 0.f : -100.f;
                s1 += (((rv >> 8) & 255u) == myreg) ? 0.f : -100.f;
                s2 += (((rv >> 16) & 255u) == myreg) ? 0.f : -100.f;
                s3 += ((rv >> 24) == myreg) ? 0.f : -100.f;
            }
            float p0 = __expf(s0), p1 = __expf(s1), p2 = __expf(s2), p3 = __expf(s3);
            den += (p0 + p1) + (p2 + p3);
            u32 w0, w1;
            asm("v_cvt_pk_bf16_f32 %0, %1, %2" : "=v"(w0) : "v"(p0), "v"(p1));
            asm("v_cvt_pk_bf16_f32 %0, %1, %2" : "=v"(w1) : "v"(p2), "v"(p3));
            uint2 wpair = make_uint2(w0, w1);
            *(uint2*)&Pb[wv][((c << 7) + j * 16 + quad * 4) ^ cs] = wpair;
        }
        den += __shfl_xor(den, 16, 64);
        den += __shfl_xor(den, 32, 64);
        if (quad == 0) invden_s[m] = 1.f / den;

        #pragma unroll
        for (int ks = 0; ks < 4; ks++) {
            short8 pf  = *(const short8*)&Pb[wv][((c << 7) + ks * 32 + quad * 8) ^ cs];
            short8 vf0 = *(const short8*)&Vt[((c << 7) + ks * 32 + quad * 8) ^ cs];
            short8 vf1 = (c < 8) ? *(const short8*)&Vt[(((16 + c) << 7) + ks * 32 + quad * 8) ^ cs] : z8;
            o_acc[i][0] = __builtin_amdgcn_mfma_f32_16x16x32_bf16(pf, vf0, o_acc[i][0], 0, 0, 0);
            o_acc[i][1] = __builtin_amdgcn_mfma_f32_16x16x32_bf16(pf, vf1, o_acc[i][1], 0, 0, 0);
        }
    }

    // ---- park O (f32) in the wave's P region for coalesced write-out ----
    float* ob = (float*)&Pb[wv][0];                // [32][26] f32 = 3328 B <= 4096 B
    #pragma unroll
    for (int i = 0; i < 2; i++)
        #pragma unroll
        for (int jv = 0; jv < 2; jv++) {
            int d = jv * 16 + c;
            if (d < 24) {
                #pragma unroll
                for (int r = 0; r < 4; r++)
                    ob[(i * 16 + quad * 4 + r) * 26 + d] = o_acc[i][jv][r];
            }
        }
    __syncthreads();

    if (tid < 128) {
        const float2* ol = (const float2*)((const float*)&Pb[0][0]
                                           + (tid >> 5) * 1024 + (tid & 31) * 26);
        float inv = invden_s[tid];
        u32* orow = (u32*)tok_out + ((size_t)((win_base + win) * 128 + tid)) * 72 + head * 12;
        #pragma unroll
        for (int d2 = 0; d2 < 12; d2++) {
            float2 v = ol[d2];
            orow[d2] = pack2(v.x * inv, v.y * inv);
        }
    }
}

// ---------------- final LN + transpose to (b, d, c, h, w), f32 out ----------------
__global__ __launch_bounds__(256) void final_ln_out_kernel(
    const u16* __restrict__ gsrc, const float* __restrict__ g, const float* __restrict__ bt,
    float* __restrict__ out)
{
    int bh = blockIdx.x;
    int h = bh % 96, d = (bh / 96) % 6, b = bh / 576;
    __shared__ u16 tile[96][152];      // bf16 tile: 29.2 KB -> 5 blocks/CU
    __shared__ float stat[96][2];
    const u16* src = gsrc + (size_t)bh * 96 * 144;
    for (int i = threadIdx.x; i < 1728; i += 256) {       // 96 rows x 18 short8
        int wt = i / 18, c8 = i - wt * 18;
        *(short8*)&tile[wt][c8 * 8] = *(const short8*)&src[wt * 144 + c8 * 8];
    }
    __syncthreads();
    if (threadIdx.x < 96) {
        const u32* row = (const u32*)&tile[threadIdx.x][0];
        float s = 0.f, s2 = 0.f;
        #pragma unroll
        for (int j = 0; j < 72; j++) {
            float lo, hi; unpack2(row[j], lo, hi);
            s += lo + hi; s2 += lo * lo + hi * hi;
        }
        float mu = s * (1.f / 144.f);
        float var = s2 * (1.f / 144.f) - mu * mu;
        stat[threadIdx.x][0] = mu;
        stat[threadIdx.x][1] = rsqrtf(fmaxf(var, 0.f) + 1e-5f);
    }
    __syncthreads();
    size_t obase = ((size_t)(b * 6 + d) * 144) * 9216 + h * 96;
    for (int i = threadIdx.x; i < 96 * 144; i += blockDim.x) {
        int c = i / 96, wt = i - c * 96;
        out[obase + (size_t)c * 9216 + wt] =
            (bf2f(tile[wt][c]) - stat[wt][0]) * stat[wt][1] * g[c] + bt[c];
    }
}

extern "C" void kernel_launch(void* const* d_in, const int* in_sizes, int n_in,
                              void* d_out, int out_size, void* d_ws, size_t ws_size,
                              hipStream_t stream) {
    const float* x     = (const float*)d_in[0];
    const float* convw = (const float*)d_in[1];
    const float* convb = (const float*)d_in[2];
    const float* ln0g  = (const float*)d_in[3];
    const float* ln0b  = (const float*)d_in[4];
    const float* n1g   = (const float*)d_in[5];
    const float* n1b   = (const float*)d_in[6];
    const float* qkvw  = (const float*)d_in[7];
    const float* qkvb  = (const float*)d_in[8];
    const float* rpb   = (const float*)d_in[9];
    const float* projw = (const float*)d_in[10];
    const float* projb = (const float*)d_in[11];
    const float* n2g   = (const float*)d_in[12];
    const float* n2b   = (const float*)d_in[13];
    const float* fc1w  = (const float*)d_in[14];
    const float* fc1b  = (const float*)d_in[15];
    const float* fc2w  = (const float*)d_in[16];
    const float* fc2b  = (const float*)d_in[17];
    const float* linw  = (const float*)d_in[18];
    const float* linb  = (const float*)d_in[19];
    const float* ln1g  = (const float*)d_in[20];
    const float* ln1b  = (const float*)d_in[21];

    // ws layout: f fp32 | tok bf16 | wbuf | bexp | qkvbuf (rest; sized by ws_size)
    char* wp = (char*)d_ws;
    float* f    = (float*)wp;             wp += (size_t)TS * 4;
    u16*   tok  = (u16*)wp;               wp += (size_t)TS * 2;
    u16*   wbuf = (u16*)wp;               wp += 352512ull * 2;
    float* bexp = (float*)wp;             wp += 196608ull * 4;
    u16*   qkvbuf = (u16*)wp;
    size_t rest = ws_size - (size_t)(wp - (char*)d_ws);
    // attention chunk count: qkv buffer is NTOK*432 bf16 / nch
    int nch = (rest >= (size_t)NTOK * 432 * 2) ? 1
            : (rest >= (size_t)NTOK * 216 * 2) ? 2 : 4;
    // MLP chunk count: hidden buffer is NTOK*288 bf16 / nm
    int nm  = (rest >= (size_t)NTOK * 288 * 2) ? 1
            : (rest >= (size_t)NTOK * 144 * 2) ? 2 : 3;
    float* y0 = (float*)d_out;   // conv+LN0 output parked in d_out until the end

    convert_weights<<<2145, 256, 0, stream>>>(qkvw, projw, fc1w, fc2w, linw, wbuf, rpb, bexp);
    conv_ln0_row<<<1152, 256, 0, stream>>>(x, convw, convb, ln0g, ln0b, y0);

    for (int layer = 0; layer < 2; ++layer) {
        const u16* qw  = wbuf + (size_t)layer * 62208;
        const u16* pw  = wbuf + 124416 + (size_t)layer * 20736;
        const u16* f1w = wbuf + 165888 + (size_t)layer * 41472;
        const u16* f2w = wbuf + 248832 + (size_t)layer * 41472;
        const float* qb  = qkvb + (size_t)layer * 432;
        const float* pb  = projb + (size_t)layer * 144;
        const float* g1  = n1g + layer * 144;
        const float* b1  = n1b + layer * 144;
        const float* g2  = n2g + layer * 144;
        const float* b2  = n2b + layer * 144;
        const float* f1b = fc1b + (size_t)layer * 288;
        const float* f2b = fc2b + (size_t)layer * 144;
        const float* bx  = bexp + (size_t)layer * 98304;

        // LN1 + roll + window partition -> tok (windowed bf16 rows)
        // layer 0 reads conv+LN0 output (y0); layer 1 reads the residual stream f
        if (layer == 0) ln_gather<1><<<NTOK / 4, 256, 0, stream>>>(y0, tok, g1, b1);
        else            ln_gather<2><<<NTOK / 4, 256, 0, stream>>>(f, tok, g1, b1);

        // attention in nch token chunks; attn output overwrites tok rows of its chunk
        int chtok = NTOK / nch, chwin = NWIN / nch;
        for (int c = 0; c < nch; c++) {
            mgemm<2, 6, 0, 1, 1, 3><<<dim3(1, chtok / 64), 192, 0, stream>>>(
                tok, qw, qb, qkvbuf, nullptr, nullptr,
                c * chtok, 144, 144, chtok, 0);
            if (layer == 0)
                attn_mfma<0><<<dim3(chwin, 6), 256, 0, stream>>>(qkvbuf, bx, tok, c * chwin, chtok);
            else
                attn_mfma<1><<<dim3(chwin, 6), 256, 0, stream>>>(qkvbuf, bx, tok, c * chwin, chtok);
        }

        // proj + window-reverse scatter into f
        // layer 0: f = y0 + proj (f not yet initialized); layer 1: f += proj
        if (layer == 0)
            mgemm<2, 5, 0, 1, 1, 1><<<dim3(1, NTOK / 64), 192, 0, stream>>>(
                tok, pw, pb, nullptr, f, y0, 0, 144, 144, 144, 0);
        else
            mgemm<2, 2, 1, 1, 1, 1><<<dim3(1, NTOK / 64), 192, 0, stream>>>(
                tok, pw, pb, nullptr, f, nullptr, 0, 144, 144, 144, 0);

        // LN2 (identity order) -> tok
        ln_gather<0><<<NTOK / 4, 256, 0, stream>>>(f, tok, g2, b2);

        // MLP in nm chunks (hidden lives in qkvbuf: fcch x 288 bf16)
        int fcch = NTOK / nm;
        for (int c = 0; c < nm; c++) {
            int mst = c * fcch;
            mgemm<2, 1, 0, 1, 1, 2><<<dim3(1, fcch / 64), 192, 0, stream>>>(
                tok, f1w, f1b, qkvbuf, nullptr, nullptr, mst, 144, 144, 288, 0);
            mgemm<2, 3, 0, 1, 2, 1><<<dim3(1, fcch / 64), 192, 0, stream>>>(
                qkvbuf, f2w, f2b, nullptr, f, nullptr, 0, 288, 288, 144, mst);
        }
    }

    // final linear + conv-residual y0 -> tok (bf16, spatial rows)
    mgemm<0, 4, 0, 1, 1, 1><<<dim3(1, NTOK / 64), 192, 0, stream>>>(
        f, wbuf + 331776, linb, tok, nullptr, y0, 0, 144, 144, 144, 0);

    // trailing LN + transpose to (n, d, c, h, w), fp32 out
    final_ln_out_kernel<<<2 * 6 * 96, 256, 0, stream>>>(tok, ln1g, ln1b, (float*)d_out);
}

// Round 9
// 839.946 us; speedup vs baseline: 1.0832x; 1.0151x over previous
//
#include <hip/hip_runtime.h>
#include <math.h>

#define NTOK 110592      // B*D*H*W = 2*6*96*96
#define NWIN 864         // 2 * 3 * 12 * 12
#define TS   15925248    // NTOK*144

typedef unsigned short u16;
typedef unsigned int   u32;
typedef __attribute__((ext_vector_type(8))) short short8;
typedef __attribute__((ext_vector_type(4))) float float4v;

__device__ __forceinline__ float bf2f(u16 v) { return __uint_as_float(((u32)v) << 16); }
__device__ __forceinline__ u16 f2bf(float f) {
    u32 u = __float_as_uint(f);
    u32 r = u + 0x7fffu + ((u >> 16) & 1u);
    return (u16)(r >> 16);
}
__device__ __forceinline__ void unpack2(u32 u, float& lo, float& hi) {
    lo = __uint_as_float(u << 16);
    hi = __uint_as_float(u & 0xffff0000u);
}
__device__ __forceinline__ u32 pack2(float lo, float hi) {
    return (u32)f2bf(lo) | ((u32)f2bf(hi) << 16);
}
__device__ __forceinline__ float wave_sum(float v) {
    #pragma unroll
    for (int o = 32; o > 0; o >>= 1) v += __shfl_xor(v, o, 64);
    return v;
}

// windowed token index -> source spatial coords (handles roll for shifted layers)
__device__ __forceinline__ void win_to_src(int tw, int shifted, int& sb, int& sd, int& sh, int& sw) {
    int n = tw & 127;
    int win = tw >> 7;
    int ww = win % 12;
    int wh = (win / 12) % 12;
    int rest = win / 144;
    int wd = rest % 3;
    sb = rest / 3;
    int ld = n >> 6, lh = (n >> 3) & 7, lw = n & 7;
    int dr = wd * 2 + ld, hr = wh * 8 + lh, wr = ww * 8 + lw;
    if (shifted) {
        sd = (dr + 1) % 6;
        sh = (hr + 4) % 96;
        sw = (wr + 4) % 96;
    } else {
        sd = dr; sh = hr; sw = wr;
    }
}

// region id of window-local token t for the shifted-window mask
__device__ __forceinline__ int tok_region(int t, int wdn, int whn, int wwn) {
    int dr = wdn * 2 + (t >> 6), hr = whn * 8 + ((t >> 3) & 7), wr = wwn * 8 + (t & 7);
    int rd = (dr < 4) ? 0 : ((dr < 5) ? 1 : 2);
    int rh = (hr < 88) ? 0 : ((hr < 92) ? 1 : 2);
    int rw = (wr < 88) ? 0 : ((wr < 92) ? 1 : 2);
    return rd * 9 + rh * 3 + rw;
}

// ---------------- weight pre-conversion fp32 -> bf16 + bias-table expansion ----------------
// wbuf layout (u16 offsets): qkvw 0 (2x62208) | projw 124416 (2x20736) | fc1w 165888 (2x41472)
//                            | fc2w 248832 (2x41472) | linw 331776 (20736); total 352512
// bexp: [layer][head][128][128] f32 relative-position bias (196608 floats)
__global__ __launch_bounds__(256) void convert_weights(
    const float* __restrict__ qkvw, const float* __restrict__ projw,
    const float* __restrict__ fc1w, const float* __restrict__ fc2w,
    const float* __restrict__ linw, u16* __restrict__ wbuf,
    const float* __restrict__ rpb, float* __restrict__ bexp)
{
    int i = blockIdx.x * 256 + threadIdx.x;
    if (i < 124416) wbuf[i] = f2bf(qkvw[i]);
    else if (i < 165888) wbuf[i] = f2bf(projw[i - 124416]);
    else if (i < 248832) wbuf[i] = f2bf(fc1w[i - 165888]);
    else if (i < 331776) wbuf[i] = f2bf(fc2w[i - 248832]);
    else if (i < 352512) wbuf[i] = f2bf(linw[i - 331776]);
    else if (i < 549120) {
        int k = i - 352512;
        int n = k & 127, m = (k >> 7) & 127;
        int lh = k >> 14;
        int h = lh % 6, l = lh / 6;
        int rdi = (m >> 6) - (n >> 6) + 1;
        int rhi = ((m >> 3) & 7) - ((n >> 3) & 7) + 7;
        int rwi = (m & 7) - (n & 7) + 7;
        int bi = (rdi * 15 + rhi) * 15 + rwi;
        bexp[k] = rpb[l * 4050 + bi * 6 + h];
    }
}

// ---------------- conv3d(1x3x3) + bias + LN0, block = (b,d,h) row of 96 positions ----------------
__global__ __launch_bounds__(256) void conv_ln0_row(
    const float* __restrict__ x, const float* __restrict__ cw, const float* __restrict__ cb,
    const float* __restrict__ g0, const float* __restrict__ b0,
    float* __restrict__ y0)
{
    int bh = blockIdx.x;                 // (b*6+d)*96 + h
    int h = bh % 96, bd = bh / 96;
    int b = bd / 6, d = bd - b * 6;
    __shared__ float ws[192][29];        // conv weights, rows 144..191 zero; stride 29 -> conflict-free
    __shared__ float xsr[9][100];        // (ci*3+kh) x (w+pad)
    __shared__ float cbias[192], gg[144], bbv[144];
    int tid = threadIdx.x;

    for (int i = tid; i < 9 * 98; i += 256) {
        int row = i / 98, wx = i - row * 98;
        int ci = row / 3, kh = row - 3 * ci;
        int hh = h + kh - 1, wsrc = wx - 1;
        float v = 0.f;
        if (hh >= 0 && hh < 96 && wsrc >= 0 && wsrc < 96)
            v = x[((((size_t)b * 6 + d) * 3 + ci) * 96 + hh) * 96 + wsrc];
        xsr[row][wx] = v;
    }
    for (int i = tid; i < 192 * 27; i += 256) {
        int c = i / 27, j = i - c * 27;
        ws[c][j] = (c < 144) ? cw[c * 27 + j] : 0.f;
    }
    for (int i = tid; i < 192; i += 256) cbias[i] = (i < 144) ? cb[i] : 0.f;
    for (int i = tid; i < 144; i += 256) { gg[i] = g0[i]; bbv[i] = b0[i]; }
    __syncthreads();

    int wv = tid >> 6, lane = tid & 63;
    int p0 = wv * 24;                    // wave owns 24 contiguous positions

    float a0[24], a1[24], a2[24];
    #pragma unroll
    for (int k = 0; k < 24; k++) {
        a0[k] = cbias[lane]; a1[k] = cbias[lane + 64]; a2[k] = cbias[lane + 128];
    }

    for (int cikh = 0; cikh < 9; cikh++) {
        const float* xr = &xsr[cikh][p0];
        float xv[26];
        #pragma unroll
        for (int t = 0; t < 26; t++) xv[t] = xr[t];   // wave-uniform broadcasts
        #pragma unroll
        for (int kw = 0; kw < 3; kw++) {
            int j = cikh * 3 + kw;
            float w0 = ws[lane][j], w1 = ws[lane + 64][j], w2 = ws[lane + 128][j];
            #pragma unroll
            for (int k = 0; k < 24; k++) {
                float xvv = xv[k + kw];
                a0[k] += w0 * xvv; a1[k] += w1 * xvv; a2[k] += w2 * xvv;
            }
        }
    }

    #pragma unroll
    for (int k = 0; k < 24; k++) {
        int p = p0 + k;
        float v0 = a0[k], v1 = a1[k];
        float v2m = (lane < 16) ? a2[k] : 0.f;
        float s  = wave_sum(v0 + v1 + v2m);
        float s2 = wave_sum(v0 * v0 + v1 * v1 + v2m * v2m);
        float mu = s * (1.f / 144.f);
        float rstd = rsqrtf(fmaxf(s2 * (1.f / 144.f) - mu * mu, 0.f) + 1e-5f);
        size_t o = ((size_t)bh * 96 + p) * 144;
        float r0 = (v0 - mu) * rstd * gg[lane] + bbv[lane];
        float r1 = (v1 - mu) * rstd * gg[lane + 64] + bbv[lane + 64];
        y0[o + lane] = r0;
        y0[o + lane + 64] = r1;
        if (lane < 16) {
            float r2 = (a2[k] - mu) * rstd * gg[lane + 128] + bbv[lane + 128];
            y0[o + lane + 128] = r2;
        }
    }
}

// ---------------- LN per token -> bf16. MODE 0: identity; MODE 1: windowed gather; MODE 2: shifted ----------------
// float2 loads + packed u32 stores.
template<int MODE>
__global__ __launch_bounds__(256) void ln_gather(
    const float* __restrict__ in, u16* __restrict__ out,
    const float* __restrict__ g, const float* __restrict__ bt)
{
    int tok = blockIdx.x * 4 + (threadIdx.x >> 6);
    int lane = threadIdx.x & 63;
    int src;
    if (MODE == 0) src = tok;
    else {
        int b, d, h, w;
        win_to_src(tok, MODE == 2, b, d, h, w);
        src = ((b * 6 + d) * 96 + h) * 96 + w;
    }
    const float2* row = (const float2*)(in + (size_t)src * 144);
    float2 a = row[lane];
    float2 b2 = (lane < 8) ? row[64 + lane] : make_float2(0.f, 0.f);
    float s  = wave_sum(a.x + a.y + b2.x + b2.y);
    float s2 = wave_sum(a.x * a.x + a.y * a.y + b2.x * b2.x + b2.y * b2.y);
    float mu = s * (1.f / 144.f);
    float rstd = rsqrtf(fmaxf(s2 * (1.f / 144.f) - mu * mu, 0.f) + 1e-5f);
    const float2* g2 = (const float2*)g;
    const float2* t2 = (const float2*)bt;
    u32* orow = (u32*)(out + (size_t)tok * 144);
    float2 gg = g2[lane], tt = t2[lane];
    orow[lane] = pack2((a.x - mu) * rstd * gg.x + tt.x, (a.y - mu) * rstd * gg.y + tt.y);
    if (lane < 8) {
        float2 gh = g2[64 + lane], th = t2[64 + lane];
        orow[64 + lane] = pack2((b2.x - mu) * rstd * gh.x + th.x, (b2.y - mu) * rstd * gh.y + th.y);
    }
}

// ---------------- MFMA GEMM: C[M,N] = A[M,144*KTILES] @ W^T (+bias), tile 64x144, 192 thr ----------------
// A staged in LDS (vectorized 16B); B fragments read DIRECTLY from global (L1/L2-hot weights).
// AMODE: 0 fp32 A rows; 2 bf16 A rows; 3 bf16 chunked head-major A (attn output; a_ld = chunk tokens).
// EPI: 0 store bf16; 1 gelu->bf16; 2 scatter-add f32 (win_to_src); 3 add f32; 4 (y0+v)->bf16;
//      5 scatter f32 = y0[orow] + v (win_to_src);
//      6 head-major qkv store: out[((head*o_ld)+orow)*72 + slot*24 + d], q pre-scaled (o_ld = rows/head).
template<int AMODE, int EPI, int SHIFTED, int ADDBIAS, int KTILES>
__global__ __launch_bounds__(192) void mgemm(
    const void* __restrict__ Asrc, const u16* __restrict__ Wt, const float* __restrict__ bias,
    u16* __restrict__ outb, float* __restrict__ fres, const float* __restrict__ y0,
    int a_add, int a_ld, int w_ld, int o_ld, int o_add)
{
    __shared__ u16 As[64 * 152];
    int m0 = blockIdx.y * 64, n0 = blockIdx.x * 144;
    int tid = threadIdx.x;
    int wv3 = tid / 64, lane = tid & 63;
    int mrow = lane & 15, quad = lane >> 4;
    const short8 z8 = {0, 0, 0, 0, 0, 0, 0, 0};

    float4v acc[4][3];
    #pragma unroll
    for (int i = 0; i < 4; i++)
        #pragma unroll
        for (int j = 0; j < 3; j++) acc[i][j] = (float4v){0.f, 0.f, 0.f, 0.f};

    #pragma unroll
    for (int kt = 0; kt < KTILES; kt++) {
        if (kt) __syncthreads();
        // stage A (64 x 144 bf16), k-slice kt, 16B vector chunks
        if (AMODE == 2) {
            const u16* A = (const u16*)Asrc;
            #pragma unroll
            for (int idx = tid; idx < 1152; idx += 192) {   // 64 rows x 18 chunks
                int r = idx / 18, c4 = idx - r * 18;
                *(short8*)&As[r * 152 + c4 * 8] =
                    *(const short8*)&A[(size_t)(a_add + m0 + r) * a_ld + kt * 144 + c4 * 8];
            }
        } else if (AMODE == 3) {
            // chunked head-major attn output: chunk cc, layout [6][chtok][24] inside chunk region
            const u16* A = (const u16*)Asrc;
            int chtok = a_ld;
            int cc = m0 / chtok;
            int t0 = m0 - cc * chtok;
            const u16* Ac = A + (size_t)cc * chtok * 144;
            #pragma unroll
            for (int idx = tid; idx < 1152; idx += 192) {
                int r = idx / 18, c4 = idx - r * 18;
                int hh = c4 / 3, sub = c4 - hh * 3;
                *(short8*)&As[r * 152 + c4 * 8] =
                    *(const short8*)&Ac[((size_t)hh * chtok + t0 + r) * 24 + sub * 8];
            }
        } else {
            const float* A = (const float*)Asrc;
            #pragma unroll
            for (int idx = tid; idx < 2304; idx += 192) {   // 64 rows x 36 float4
                int r = idx / 36, c4 = idx - r * 36;
                const float4* src4 = (const float4*)&A[(size_t)(a_add + m0 + r) * a_ld + kt * 144];
                float4 v = src4[c4];
                *(u32*)&As[r * 152 + c4 * 4]     = pack2(v.x, v.y);
                *(u32*)&As[r * 152 + c4 * 4 + 2] = pack2(v.z, v.w);
            }
        }
        __syncthreads();

        const u16* Wg = Wt + (size_t)(n0 + wv3 * 48 + mrow) * w_ld + kt * 144;

        #pragma unroll
        for (int ks = 0; ks < 4; ks++) {
            int k0 = ks * 32;
            short8 af[4], bf[3];
            #pragma unroll
            for (int i = 0; i < 4; i++)
                af[i] = *(const short8*)&As[(i * 16 + mrow) * 152 + k0 + quad * 8];
            #pragma unroll
            for (int j = 0; j < 3; j++)
                bf[j] = *(const short8*)&Wg[(size_t)j * 16 * w_ld + k0 + quad * 8];
            #pragma unroll
            for (int i = 0; i < 4; i++)
                #pragma unroll
                for (int j = 0; j < 3; j++)
                    acc[i][j] = __builtin_amdgcn_mfma_f32_16x16x32_bf16(af[i], bf[j], acc[i][j], 0, 0, 0);
        }
        {   // K-tail 128..143: quads 2,3 supply zeros
            bool tl = (quad < 2);
            short8 af[4], bf[3];
            #pragma unroll
            for (int i = 0; i < 4; i++)
                af[i] = tl ? *(const short8*)&As[(i * 16 + mrow) * 152 + 128 + quad * 8] : z8;
            #pragma unroll
            for (int j = 0; j < 3; j++)
                bf[j] = tl ? *(const short8*)&Wg[(size_t)j * 16 * w_ld + 128 + quad * 8] : z8;
            #pragma unroll
            for (int i = 0; i < 4; i++)
                #pragma unroll
                for (int j = 0; j < 3; j++)
                    acc[i][j] = __builtin_amdgcn_mfma_f32_16x16x32_bf16(af[i], bf[j], acc[i][j], 0, 0, 0);
        }
    }

    // epilogue. C/D layout: col = lane&15 (n), row = quad*4 + reg (m)
    #pragma unroll
    for (int i = 0; i < 4; i++) {
        #pragma unroll
        for (int reg = 0; reg < 4; reg++) {
            int m = m0 + i * 16 + quad * 4 + reg;
            int orow;
            if (EPI == 2 || EPI == 5) {
                int b, d, h, w;
                win_to_src(m, SHIFTED, b, d, h, w);
                orow = ((b * 6 + d) * 96 + h) * 96 + w;
            } else orow = m + o_add;
            #pragma unroll
            for (int j = 0; j < 3; j++) {
                int n = n0 + wv3 * 48 + j * 16 + mrow;
                float v = acc[i][j][reg];
                if (ADDBIAS) v += bias[n];
                if (EPI == 1) v = 0.5f * v * (1.f + erff(v * 0.70710678118f));
                if (EPI == 2 || EPI == 3) {
                    fres[(size_t)orow * 144 + n] += v;
                } else if (EPI == 5) {
                    fres[(size_t)orow * 144 + n] = y0[(size_t)orow * 144 + n] + v;
                } else if (EPI == 6) {
                    int slot = n / 144;
                    int hn = n - slot * 144;
                    int head = hn / 24, dd = hn - head * 24;
                    if (slot == 0) v *= 0.20412414523193154f;  // q pre-scale
                    outb[((size_t)head * o_ld + orow) * 72 + slot * 24 + dd] = f2bf(v);
                } else {
                    if (EPI == 4) v += y0[(size_t)orow * o_ld + n];
                    outb[(size_t)orow * o_ld + n] = f2bf(v);
                }
            }
        }
    }
}

// ---------------- window attention via MFMA: block=(win,head), 4 waves, 32-query strip per wave ----------------
// qkv head-major [head][tok][72] (q24|k24|v24, q pre-scaled). Swapped QK^T -> in-lane softmax
// (no-max, bounded logits), cvt_pk bf16 P. Vt and Pb stride-128 rows with XOR swizzle.
// Output written HEAD-MAJOR into the chunk's own tok region: [head][chtok][24] -> coalesced
// 3KB burst per block, no cross-block partial-line write amplification.
template<int SHIFTED>
__global__ __launch_bounds__(256) void attn_mfma(
    const u16* __restrict__ qkv,        // chunk-local, head-major
    const float* __restrict__ bexp,     // layer's expanded bias [6][128][128]
    u16* __restrict__ tok_out,          // chunk base of tok region
    int win_base, int chtok)
{
    int win = blockIdx.x;
    int head = blockIdx.y;
    __shared__ __align__(16) u16 Pb[4][2048];      // per-wave P strip [16 rows][128], swizzled
    __shared__ __align__(16) u16 Vt[3072];         // V transposed [24 d-rows][128 tok], swizzled
    __shared__ float invden_s[128];
    __shared__ u32 reg_pack[32];                   // 4 packed region bytes per entry

    int tid = threadIdx.x;
    int wv = tid >> 6, lane = tid & 63;
    int c = lane & 15, quad = lane >> 4;
    int qbase = wv * 32;
    const short8 z8 = {0, 0, 0, 0, 0, 0, 0, 0};
    const float* bh_ = bexp + head * 16384;
    const u16* base = qkv + ((size_t)head * chtok + (size_t)win * 128) * 72;
    int cs = (c & 7) << 3;                          // this lane's row-swizzle (rows c and 16+c)

    int wdn = 0, whn = 0, wwn = 0;
    if (SHIFTED) {
        int wib = (win_base + win) % 432;
        wwn = wib % 12; whn = (wib / 12) % 12; wdn = wib / 144;
    }

    // ---- stage V transposed + swizzled, packed mask regions ----
    if (tid < 128) {
        const u32* vsrc = (const u32*)(base + (size_t)tid * 72 + 48);
        #pragma unroll
        for (int i = 0; i < 12; i++) {
            u32 u = vsrc[i];
            int d0 = 2 * i, d1 = 2 * i + 1;
            Vt[((d0 << 7) + tid) ^ ((d0 & 7) << 3)] = (u16)(u & 0xffffu);
            Vt[((d1 << 7) + tid) ^ ((d1 & 7) << 3)] = (u16)(u >> 16);
        }
    }
    if (SHIFTED && tid < 32) {
        int t0 = tid * 4;
        reg_pack[tid] = (u32)tok_region(t0, wdn, whn, wwn)
                      | ((u32)tok_region(t0 + 1, wdn, whn, wwn) << 8)
                      | ((u32)tok_region(t0 + 2, wdn, whn, wwn) << 16)
                      | ((u32)tok_region(t0 + 3, wdn, whn, wwn) << 24);
    }
    __syncthreads();

    // ---- Q fragments (B-operand): rows qbase + i*16 + c ----
    short8 aq[2];
    #pragma unroll
    for (int i = 0; i < 2; i++) {
        aq[i] = z8;
        if (quad < 3)
            aq[i] = *(const short8*)(base + (size_t)(qbase + i * 16 + c) * 72 + quad * 8);
    }

    // ---- S^T = K Q^T (swapped operands): lane holds S[q=i*16+c][k=j*16+quad*4+r] ----
    float4v s_acc[2][8];
    #pragma unroll
    for (int i = 0; i < 2; i++)
        #pragma unroll
        for (int j = 0; j < 8; j++) s_acc[i][j] = (float4v){0.f, 0.f, 0.f, 0.f};

    #pragma unroll
    for (int j = 0; j < 8; j++) {
        short8 kf = z8;
        if (quad < 3)
            kf = *(const short8*)(base + (size_t)(j * 16 + c) * 72 + 24 + quad * 8);
        s_acc[0][j] = __builtin_amdgcn_mfma_f32_16x16x32_bf16(kf, aq[0], s_acc[0][j], 0, 0, 0);
        s_acc[1][j] = __builtin_amdgcn_mfma_f32_16x16x32_bf16(kf, aq[1], s_acc[1][j], 0, 0, 0);
    }

    float4v o_acc[2][2];
    #pragma unroll
    for (int i = 0; i < 2; i++)
        #pragma unroll
        for (int jv = 0; jv < 2; jv++) o_acc[i][jv] = (float4v){0.f, 0.f, 0.f, 0.f};

    // ---- per 16-query half: no-max softmax (in-lane) -> P(bf16, swizzled LDS) -> PV MFMA ----
    #pragma unroll
    for (int i = 0; i < 2; i++) {
        int m = qbase + i * 16 + c;
        const float* brow = bh_ + m * 128;
        u32 myreg = SHIFTED ? (u32)tok_region(m, wdn, whn, wwn) : 0u;
        float den = 0.f;
        #pragma unroll
        for (int j = 0; j < 8; j++) {
            float4 bv = *(const float4*)(brow + j * 16 + quad * 4);
            float s0 = s_acc[i][j][0] + bv.x;
            float s1 = s_acc[i][j][1] + bv.y;
            float s2 = s_acc[i][j][2] + bv.z;
            float s3 = s_acc[i][j][3] + bv.w;
            if (SHIFTED) {
                u32 rv = reg_pack[j * 4 + quad];
                s0 += ((rv & 255u) == myreg) ? 0.f : -100.f;
                s1 += (((rv >> 8) & 255u) == myreg) ? 0.f : -100.f;
                s2 += (((rv >> 16) & 255u) == myreg) ? 0.f : -100.f;
                s3 += ((rv >> 24) == myreg) ? 0.f : -100.f;
            }
            float p0 = __expf(s0), p1 = __expf(s1), p2 = __expf(s2), p3 = __expf(s3);
            den += (p0 + p1) + (p2 + p3);
            u32 w0, w1;
            asm("v_cvt_pk_bf16_f32 %0, %1, %2" : "=v"(w0) : "v"(p0), "v"(p1));
            asm("v_cvt_pk_bf16_f32 %0, %1, %2" : "=v"(w1) : "v"(p2), "v"(p3));
            uint2 wpair = make_uint2(w0, w1);
            *(uint2*)&Pb[wv][((c << 7) + j * 16 + quad * 4) ^ cs] = wpair;
        }
        den += __shfl_xor(den, 16, 64);
        den += __shfl_xor(den, 32, 64);
        if (quad == 0) invden_s[m] = 1.f / den;

        #pragma unroll
        for (int ks = 0; ks < 4; ks++) {
            short8 pf  = *(const short8*)&Pb[wv][((c << 7) + ks * 32 + quad * 8) ^ cs];
            short8 vf0 = *(const short8*)&Vt[((c << 7) + ks * 32 + quad * 8) ^ cs];
            short8 vf1 = (c < 8) ? *(const short8*)&Vt[(((16 + c) << 7) + ks * 32 + quad * 8) ^ cs] : z8;
            o_acc[i][0] = __builtin_amdgcn_mfma_f32_16x16x32_bf16(pf, vf0, o_acc[i][0], 0, 0, 0);
            o_acc[i][1] = __builtin_amdgcn_mfma_f32_16x16x32_bf16(pf, vf1, o_acc[i][1], 0, 0, 0);
        }
    }

    // ---- park O (f32) in the wave's P region for coalesced write-out ----
    float* ob = (float*)&Pb[wv][0];                // [32][26] f32 = 3328 B <= 4096 B
    #pragma unroll
    for (int i = 0; i < 2; i++)
        #pragma unroll
        for (int jv = 0; jv < 2; jv++) {
            int d = jv * 16 + c;
            if (d < 24) {
                #pragma unroll
                for (int r = 0; r < 4; r++)
                    ob[(i * 16 + quad * 4 + r) * 26 + d] = o_acc[i][jv][r];
            }
        }
    __syncthreads();

    if (tid < 128) {
        const float2* ol = (const float2*)((const float*)&Pb[0][0]
                                           + (tid >> 5) * 1024 + (tid & 31) * 26);
        float inv = invden_s[tid];
        // head-major chunk-local output: [head][chtok][24]
        u32* orow = (u32*)tok_out + ((size_t)head * chtok + (size_t)win * 128 + tid) * 12;
        #pragma unroll
        for (int d2 = 0; d2 < 12; d2++) {
            float2 v = ol[d2];
            orow[d2] = pack2(v.x * inv, v.y * inv);
        }
    }
}

// ---------------- final LN + transpose to (b, d, c, h, w), f32 out ----------------
__global__ __launch_bounds__(256) void final_ln_out_kernel(
    const u16* __restrict__ gsrc, const float* __restrict__ g, const float* __restrict__ bt,
    float* __restrict__ out)
{
    int bh = blockIdx.x;
    int h = bh % 96, d = (bh / 96) % 6, b = bh / 576;
    __shared__ u16 tile[96][152];      // bf16 tile: 29.2 KB -> 5 blocks/CU
    __shared__ float stat[96][2];
    const u16* src = gsrc + (size_t)bh * 96 * 144;
    for (int i = threadIdx.x; i < 1728; i += 256) {       // 96 rows x 18 short8
        int wt = i / 18, c8 = i - wt * 18;
        *(short8*)&tile[wt][c8 * 8] = *(const short8*)&src[wt * 144 + c8 * 8];
    }
    __syncthreads();
    if (threadIdx.x < 96) {
        const u32* row = (const u32*)&tile[threadIdx.x][0];
        float s = 0.f, s2 = 0.f;
        #pragma unroll
        for (int j = 0; j < 72; j++) {
            float lo, hi; unpack2(row[j], lo, hi);
            s += lo + hi; s2 += lo * lo + hi * hi;
        }
        float mu = s * (1.f / 144.f);
        float var = s2 * (1.f / 144.f) - mu * mu;
        stat[threadIdx.x][0] = mu;
        stat[threadIdx.x][1] = rsqrtf(fmaxf(var, 0.f) + 1e-5f);
    }
    __syncthreads();
    size_t obase = ((size_t)(b * 6 + d) * 144) * 9216 + h * 96;
    for (int i = threadIdx.x; i < 96 * 144; i += blockDim.x) {
        int c = i / 96, wt = i - c * 96;
        out[obase + (size_t)c * 9216 + wt] =
            (bf2f(tile[wt][c]) - stat[wt][0]) * stat[wt][1] * g[c] + bt[c];
    }
}

extern "C" void kernel_launch(void* const* d_in, const int* in_sizes, int n_in,
                              void* d_out, int out_size, void* d_ws, size_t ws_size,
                              hipStream_t stream) {
    const float* x     = (const float*)d_in[0];
    const float* convw = (const float*)d_in[1];
    const float* convb = (const float*)d_in[2];
    const float* ln0g  = (const float*)d_in[3];
    const float* ln0b  = (const float*)d_in[4];
    const float* n1g   = (const float*)d_in[5];
    const float* n1b   = (const float*)d_in[6];
    const float* qkvw  = (const float*)d_in[7];
    const float* qkvb  = (const float*)d_in[8];
    const float* rpb   = (const float*)d_in[9];
    const float* projw = (const float*)d_in[10];
    const float* projb = (const float*)d_in[11];
    const float* n2g   = (const float*)d_in[12];
    const float* n2b   = (const float*)d_in[13];
    const float* fc1w  = (const float*)d_in[14];
    const float* fc1b  = (const float*)d_in[15];
    const float* fc2w  = (const float*)d_in[16];
    const float* fc2b  = (const float*)d_in[17];
    const float* linw  = (const float*)d_in[18];
    const float* linb  = (const float*)d_in[19];
    const float* ln1g  = (const float*)d_in[20];
    const float* ln1b  = (const float*)d_in[21];

    // ws layout: f fp32 | tok bf16 | wbuf | bexp | qkvbuf (rest; sized by ws_size)
    char* wp = (char*)d_ws;
    float* f    = (float*)wp;             wp += (size_t)TS * 4;
    u16*   tok  = (u16*)wp;               wp += (size_t)TS * 2;
    u16*   wbuf = (u16*)wp;               wp += 352512ull * 2;
    float* bexp = (float*)wp;             wp += 196608ull * 4;
    u16*   qkvbuf = (u16*)wp;
    size_t rest = ws_size - (size_t)(wp - (char*)d_ws);
    // attention chunk count: qkv buffer is NTOK*432 bf16 / nch
    int nch = (rest >= (size_t)NTOK * 432 * 2) ? 1
            : (rest >= (size_t)NTOK * 216 * 2) ? 2 : 4;
    // MLP chunk count: hidden buffer is NTOK*288 bf16 / nm
    int nm  = (rest >= (size_t)NTOK * 288 * 2) ? 1
            : (rest >= (size_t)NTOK * 144 * 2) ? 2 : 3;
    float* y0 = (float*)d_out;   // conv+LN0 output parked in d_out until the end

    convert_weights<<<2145, 256, 0, stream>>>(qkvw, projw, fc1w, fc2w, linw, wbuf, rpb, bexp);
    conv_ln0_row<<<1152, 256, 0, stream>>>(x, convw, convb, ln0g, ln0b, y0);

    for (int layer = 0; layer < 2; ++layer) {
        const u16* qw  = wbuf + (size_t)layer * 62208;
        const u16* pw  = wbuf + 124416 + (size_t)layer * 20736;
        const u16* f1w = wbuf + 165888 + (size_t)layer * 41472;
        const u16* f2w = wbuf + 248832 + (size_t)layer * 41472;
        const float* qb  = qkvb + (size_t)layer * 432;
        const float* pb  = projb + (size_t)layer * 144;
        const float* g1  = n1g + layer * 144;
        const float* b1  = n1b + layer * 144;
        const float* g2  = n2g + layer * 144;
        const float* b2  = n2b + layer * 144;
        const float* f1b = fc1b + (size_t)layer * 288;
        const float* f2b = fc2b + (size_t)layer * 144;
        const float* bx  = bexp + (size_t)layer * 98304;

        // LN1 + roll + window partition -> tok (windowed bf16 rows)
        // layer 0 reads conv+LN0 output (y0); layer 1 reads the residual stream f
        if (layer == 0) ln_gather<1><<<NTOK / 4, 256, 0, stream>>>(y0, tok, g1, b1);
        else            ln_gather<2><<<NTOK / 4, 256, 0, stream>>>(f, tok, g1, b1);

        // attention in nch token chunks; attn output overwrites its chunk's tok region
        // in head-major [6][chtok][24] layout (coalesced per-block writes)
        int chtok = NTOK / nch, chwin = NWIN / nch;
        for (int c = 0; c < nch; c++) {
            mgemm<2, 6, 0, 1, 1><<<dim3(3, chtok / 64), 192, 0, stream>>>(
                tok, qw, qb, qkvbuf, nullptr, nullptr,
                c * chtok, 144, 144, chtok, 0);
            u16* ob = tok + (size_t)c * chtok * 144;
            if (layer == 0)
                attn_mfma<0><<<dim3(chwin, 6), 256, 0, stream>>>(qkvbuf, bx, ob, c * chwin, chtok);
            else
                attn_mfma<1><<<dim3(chwin, 6), 256, 0, stream>>>(qkvbuf, bx, ob, c * chwin, chtok);
        }

        // proj (AMODE 3: chunked head-major A) + window-reverse scatter into f
        // layer 0: f = y0 + proj (f not yet initialized); layer 1: f += proj
        if (layer == 0)
            mgemm<3, 5, 0, 1, 1><<<dim3(1, NTOK / 64), 192, 0, stream>>>(
                tok, pw, pb, nullptr, f, y0, 0, chtok, 144, 144, 0);
        else
            mgemm<3, 2, 1, 1, 1><<<dim3(1, NTOK / 64), 192, 0, stream>>>(
                tok, pw, pb, nullptr, f, nullptr, 0, chtok, 144, 144, 0);

        // LN2 (identity order) -> tok
        ln_gather<0><<<NTOK / 4, 256, 0, stream>>>(f, tok, g2, b2);

        // MLP in nm chunks (hidden lives in qkvbuf: fcch x 288 bf16)
        int fcch = NTOK / nm;
        for (int c = 0; c < nm; c++) {
            int mst = c * fcch;
            mgemm<2, 1, 0, 1, 1><<<dim3(2, fcch / 64), 192, 0, stream>>>(
                tok, f1w, f1b, qkvbuf, nullptr, nullptr, mst, 144, 144, 288, 0);
            mgemm<2, 3, 0, 1, 2><<<dim3(1, fcch / 64), 192, 0, stream>>>(
                qkvbuf, f2w, f2b, nullptr, f, nullptr, 0, 288, 288, 144, mst);
        }
    }

    // final linear + conv-residual y0 -> tok (bf16, spatial rows)
    mgemm<0, 4, 0, 1, 1><<<dim3(1, NTOK / 64), 192, 0, stream>>>(
        f, wbuf + 331776, linb, tok, nullptr, y0, 0, 144, 144, 144, 0);

    // trailing LN + transpose to (n, d, c, h, w), fp32 out
    final_ln_out_kernel<<<2 * 6 * 96, 256, 0, stream>>>(tok, ln1g, ln1b, (float*)d_out);
}

// Round 10
// 789.598 us; speedup vs baseline: 1.1523x; 1.0638x over previous
//
#include <hip/hip_runtime.h>
#include <math.h>

#define NTOK 110592      // B*D*H*W = 2*6*96*96
#define NWIN 864         // 2 * 3 * 12 * 12
#define TS   15925248    // NTOK*144

typedef unsigned short u16;
typedef unsigned int   u32;
typedef __attribute__((ext_vector_type(8))) short short8;
typedef __attribute__((ext_vector_type(4))) float float4v;

__device__ __forceinline__ float bf2f(u16 v) { return __uint_as_float(((u32)v) << 16); }
__device__ __forceinline__ u16 f2bf(float f) {
    u32 u = __float_as_uint(f);
    u32 r = u + 0x7fffu + ((u >> 16) & 1u);
    return (u16)(r >> 16);
}
__device__ __forceinline__ void unpack2(u32 u, float& lo, float& hi) {
    lo = __uint_as_float(u << 16);
    hi = __uint_as_float(u & 0xffff0000u);
}
__device__ __forceinline__ u32 pack2(float lo, float hi) {
    return (u32)f2bf(lo) | ((u32)f2bf(hi) << 16);
}
__device__ __forceinline__ float wave_sum(float v) {
    #pragma unroll
    for (int o = 32; o > 0; o >>= 1) v += __shfl_xor(v, o, 64);
    return v;
}

// windowed token index -> source spatial coords (handles roll for shifted layers)
__device__ __forceinline__ void win_to_src(int tw, int shifted, int& sb, int& sd, int& sh, int& sw) {
    int n = tw & 127;
    int win = tw >> 7;
    int ww = win % 12;
    int wh = (win / 12) % 12;
    int rest = win / 144;
    int wd = rest % 3;
    sb = rest / 3;
    int ld = n >> 6, lh = (n >> 3) & 7, lw = n & 7;
    int dr = wd * 2 + ld, hr = wh * 8 + lh, wr = ww * 8 + lw;
    if (shifted) {
        sd = (dr + 1) % 6;
        sh = (hr + 4) % 96;
        sw = (wr + 4) % 96;
    } else {
        sd = dr; sh = hr; sw = wr;
    }
}

// region id of window-local token t for the shifted-window mask
__device__ __forceinline__ int tok_region(int t, int wdn, int whn, int wwn) {
    int dr = wdn * 2 + (t >> 6), hr = whn * 8 + ((t >> 3) & 7), wr = wwn * 8 + (t & 7);
    int rd = (dr < 4) ? 0 : ((dr < 5) ? 1 : 2);
    int rh = (hr < 88) ? 0 : ((hr < 92) ? 1 : 2);
    int rw = (wr < 88) ? 0 : ((wr < 92) ? 1 : 2);
    return rd * 9 + rh * 3 + rw;
}

// ---------------- weight pre-conversion fp32 -> bf16 + bias-table expansion ----------------
__global__ __launch_bounds__(256) void convert_weights(
    const float* __restrict__ qkvw, const float* __restrict__ projw,
    const float* __restrict__ fc1w, const float* __restrict__ fc2w,
    const float* __restrict__ linw, u16* __restrict__ wbuf,
    const float* __restrict__ rpb, float* __restrict__ bexp)
{
    int i = blockIdx.x * 256 + threadIdx.x;
    if (i < 124416) wbuf[i] = f2bf(qkvw[i]);
    else if (i < 165888) wbuf[i] = f2bf(projw[i - 124416]);
    else if (i < 248832) wbuf[i] = f2bf(fc1w[i - 165888]);
    else if (i < 331776) wbuf[i] = f2bf(fc2w[i - 248832]);
    else if (i < 352512) wbuf[i] = f2bf(linw[i - 331776]);
    else if (i < 549120) {
        int k = i - 352512;
        int n = k & 127, m = (k >> 7) & 127;
        int lh = k >> 14;
        int h = lh % 6, l = lh / 6;
        int rdi = (m >> 6) - (n >> 6) + 1;
        int rhi = ((m >> 3) & 7) - ((n >> 3) & 7) + 7;
        int rwi = (m & 7) - (n & 7) + 7;
        int bi = (rdi * 15 + rhi) * 15 + rwi;
        bexp[k] = rpb[l * 4050 + bi * 6 + h];
    }
}

// ---------------- conv3d(1x3x3) + bias + LN0, block = (b,d,h) row of 96 positions ----------------
__global__ __launch_bounds__(256) void conv_ln0_row(
    const float* __restrict__ x, const float* __restrict__ cw, const float* __restrict__ cb,
    const float* __restrict__ g0, const float* __restrict__ b0,
    float* __restrict__ y0)
{
    int bh = blockIdx.x;                 // (b*6+d)*96 + h
    int h = bh % 96, bd = bh / 96;
    int b = bd / 6, d = bd - b * 6;
    __shared__ float ws[192][29];
    __shared__ float xsr[9][100];
    __shared__ float cbias[192], gg[144], bbv[144];
    int tid = threadIdx.x;

    for (int i = tid; i < 9 * 98; i += 256) {
        int row = i / 98, wx = i - row * 98;
        int ci = row / 3, kh = row - 3 * ci;
        int hh = h + kh - 1, wsrc = wx - 1;
        float v = 0.f;
        if (hh >= 0 && hh < 96 && wsrc >= 0 && wsrc < 96)
            v = x[((((size_t)b * 6 + d) * 3 + ci) * 96 + hh) * 96 + wsrc];
        xsr[row][wx] = v;
    }
    for (int i = tid; i < 192 * 27; i += 256) {
        int c = i / 27, j = i - c * 27;
        ws[c][j] = (c < 144) ? cw[c * 27 + j] : 0.f;
    }
    for (int i = tid; i < 192; i += 256) cbias[i] = (i < 144) ? cb[i] : 0.f;
    for (int i = tid; i < 144; i += 256) { gg[i] = g0[i]; bbv[i] = b0[i]; }
    __syncthreads();

    int wv = tid >> 6, lane = tid & 63;
    int p0 = wv * 24;

    float a0[24], a1[24], a2[24];
    #pragma unroll
    for (int k = 0; k < 24; k++) {
        a0[k] = cbias[lane]; a1[k] = cbias[lane + 64]; a2[k] = cbias[lane + 128];
    }

    for (int cikh = 0; cikh < 9; cikh++) {
        const float* xr = &xsr[cikh][p0];
        float xv[26];
        #pragma unroll
        for (int t = 0; t < 26; t++) xv[t] = xr[t];
        #pragma unroll
        for (int kw = 0; kw < 3; kw++) {
            int j = cikh * 3 + kw;
            float w0 = ws[lane][j], w1 = ws[lane + 64][j], w2 = ws[lane + 128][j];
            #pragma unroll
            for (int k = 0; k < 24; k++) {
                float xvv = xv[k + kw];
                a0[k] += w0 * xvv; a1[k] += w1 * xvv; a2[k] += w2 * xvv;
            }
        }
    }

    #pragma unroll
    for (int k = 0; k < 24; k++) {
        int p = p0 + k;
        float v0 = a0[k], v1 = a1[k];
        float v2m = (lane < 16) ? a2[k] : 0.f;
        float s  = wave_sum(v0 + v1 + v2m);
        float s2 = wave_sum(v0 * v0 + v1 * v1 + v2m * v2m);
        float mu = s * (1.f / 144.f);
        float rstd = rsqrtf(fmaxf(s2 * (1.f / 144.f) - mu * mu, 0.f) + 1e-5f);
        size_t o = ((size_t)bh * 96 + p) * 144;
        float r0 = (v0 - mu) * rstd * gg[lane] + bbv[lane];
        float r1 = (v1 - mu) * rstd * gg[lane + 64] + bbv[lane + 64];
        y0[o + lane] = r0;
        y0[o + lane + 64] = r1;
        if (lane < 16) {
            float r2 = (a2[k] - mu) * rstd * gg[lane + 128] + bbv[lane + 128];
            y0[o + lane + 128] = r2;
        }
    }
}

// ---------------- LN per token -> bf16. MODE 1: windowed gather; MODE 2: shifted ----------------
template<int MODE>
__global__ __launch_bounds__(256) void ln_gather(
    const float* __restrict__ in, u16* __restrict__ out,
    const float* __restrict__ g, const float* __restrict__ bt)
{
    int tok = blockIdx.x * 4 + (threadIdx.x >> 6);
    int lane = threadIdx.x & 63;
    int src;
    {
        int b, d, h, w;
        win_to_src(tok, MODE == 2, b, d, h, w);
        src = ((b * 6 + d) * 96 + h) * 96 + w;
    }
    const float2* row = (const float2*)(in + (size_t)src * 144);
    float2 a = row[lane];
    float2 b2 = (lane < 8) ? row[64 + lane] : make_float2(0.f, 0.f);
    float s  = wave_sum(a.x + a.y + b2.x + b2.y);
    float s2 = wave_sum(a.x * a.x + a.y * a.y + b2.x * b2.x + b2.y * b2.y);
    float mu = s * (1.f / 144.f);
    float rstd = rsqrtf(fmaxf(s2 * (1.f / 144.f) - mu * mu, 0.f) + 1e-5f);
    const float2* g2 = (const float2*)g;
    const float2* t2 = (const float2*)bt;
    u32* orow = (u32*)(out + (size_t)tok * 144);
    float2 gg = g2[lane], tt = t2[lane];
    orow[lane] = pack2((a.x - mu) * rstd * gg.x + tt.x, (a.y - mu) * rstd * gg.y + tt.y);
    if (lane < 8) {
        float2 gh = g2[64 + lane], th = t2[64 + lane];
        orow[64 + lane] = pack2((b2.x - mu) * rstd * gh.x + th.x, (b2.y - mu) * rstd * gh.y + th.y);
    }
}

// ---------------- MFMA GEMM: C[M,N] = A[M,144*KTILES] @ W^T (+bias), tile 64x144, 192 thr ----------------
// AMODE: 0 fp32 A rows; 2 bf16 A rows; 3 bf16 chunked head-major A (attn out; a_ld = chunk tokens);
//        5 fp32 A rows with FUSED LayerNorm (lng/lnb) during staging.
// EPI: 0 store bf16; 1 gelu->bf16; 2 scatter-add f32 (win_to_src); 3 add f32; 4 (y0+v)->bf16;
//      5 scatter f32 = y0[orow] + v (win_to_src);
//      6 qkv store, write-combined via LDS: layout [slot][head][chtok][24], slot=blockIdx.x,
//        q pre-scaled (o_ld = chunk tokens).
template<int AMODE, int EPI, int SHIFTED, int ADDBIAS, int KTILES>
__global__ __launch_bounds__(192) void mgemm(
    const void* __restrict__ Asrc, const u16* __restrict__ Wt, const float* __restrict__ bias,
    u16* __restrict__ outb, float* __restrict__ fres, const float* __restrict__ y0,
    const float* __restrict__ lng, const float* __restrict__ lnb,
    int a_add, int a_ld, int w_ld, int o_ld, int o_add)
{
    __shared__ u16 As[64 * 152];
    int m0 = blockIdx.y * 64, n0 = blockIdx.x * 144;
    int tid = threadIdx.x;
    int wv3 = tid / 64, lane = tid & 63;
    int mrow = lane & 15, quad = lane >> 4;
    const short8 z8 = {0, 0, 0, 0, 0, 0, 0, 0};

    float4v acc[4][3];
    #pragma unroll
    for (int i = 0; i < 4; i++)
        #pragma unroll
        for (int j = 0; j < 3; j++) acc[i][j] = (float4v){0.f, 0.f, 0.f, 0.f};

    #pragma unroll
    for (int kt = 0; kt < KTILES; kt++) {
        if (kt) __syncthreads();
        if constexpr (AMODE == 5) {
            // fused-LN staging: 3 threads per row, partial sums via LDS exchange
            __shared__ float gs[144], bs[144], ps[64][6];
            for (int i = tid; i < 144; i += 192) { gs[i] = lng[i]; bs[i] = lnb[i]; }
            int r = tid / 3, p = tid - 3 * r;
            int srow = a_add + m0 + r;
            const float4* s4 = (const float4*)((const float*)Asrc + (size_t)srow * 144) + p * 12;
            float4 av[12];
            float s = 0.f, s2 = 0.f;
            #pragma unroll
            for (int q = 0; q < 12; q++) {
                av[q] = s4[q];
                s  += (av[q].x + av[q].y) + (av[q].z + av[q].w);
                s2 += (av[q].x * av[q].x + av[q].y * av[q].y)
                    + (av[q].z * av[q].z + av[q].w * av[q].w);
            }
            ps[r][p] = s; ps[r][3 + p] = s2;
            __syncthreads();
            float S  = ps[r][0] + ps[r][1] + ps[r][2];
            float S2 = ps[r][3] + ps[r][4] + ps[r][5];
            float mu = S * (1.f / 144.f);
            float rstd = rsqrtf(fmaxf(S2 * (1.f / 144.f) - mu * mu, 0.f) + 1e-5f);
            #pragma unroll
            for (int q = 0; q < 12; q++) {
                int n = p * 48 + q * 4;
                *(u32*)&As[r * 152 + n]     = pack2((av[q].x - mu) * rstd * gs[n]     + bs[n],
                                                    (av[q].y - mu) * rstd * gs[n + 1] + bs[n + 1]);
                *(u32*)&As[r * 152 + n + 2] = pack2((av[q].z - mu) * rstd * gs[n + 2] + bs[n + 2],
                                                    (av[q].w - mu) * rstd * gs[n + 3] + bs[n + 3]);
            }
        } else if constexpr (AMODE == 2) {
            const u16* A = (const u16*)Asrc;
            #pragma unroll
            for (int idx = tid; idx < 1152; idx += 192) {   // 64 rows x 18 chunks
                int r = idx / 18, c4 = idx - r * 18;
                *(short8*)&As[r * 152 + c4 * 8] =
                    *(const short8*)&A[(size_t)(a_add + m0 + r) * a_ld + kt * 144 + c4 * 8];
            }
        } else if constexpr (AMODE == 3) {
            // chunked head-major attn output: chunk cc, layout [6][chtok][24] inside chunk region
            const u16* A = (const u16*)Asrc;
            int chtok = a_ld;
            int cc = m0 / chtok;
            int t0 = m0 - cc * chtok;
            const u16* Ac = A + (size_t)cc * chtok * 144;
            #pragma unroll
            for (int idx = tid; idx < 1152; idx += 192) {
                int r = idx / 18, c4 = idx - r * 18;
                int hh = c4 / 3, sub = c4 - hh * 3;
                *(short8*)&As[r * 152 + c4 * 8] =
                    *(const short8*)&Ac[((size_t)hh * chtok + t0 + r) * 24 + sub * 8];
            }
        } else {
            const float* A = (const float*)Asrc;
            #pragma unroll
            for (int idx = tid; idx < 2304; idx += 192) {   // 64 rows x 36 float4
                int r = idx / 36, c4 = idx - r * 36;
                const float4* src4 = (const float4*)&A[(size_t)(a_add + m0 + r) * a_ld + kt * 144];
                float4 v = src4[c4];
                *(u32*)&As[r * 152 + c4 * 4]     = pack2(v.x, v.y);
                *(u32*)&As[r * 152 + c4 * 4 + 2] = pack2(v.z, v.w);
            }
        }
        __syncthreads();

        const u16* Wg = Wt + (size_t)(n0 + wv3 * 48 + mrow) * w_ld + kt * 144;

        #pragma unroll
        for (int ks = 0; ks < 4; ks++) {
            int k0 = ks * 32;
            short8 af[4], bf[3];
            #pragma unroll
            for (int i = 0; i < 4; i++)
                af[i] = *(const short8*)&As[(i * 16 + mrow) * 152 + k0 + quad * 8];
            #pragma unroll
            for (int j = 0; j < 3; j++)
                bf[j] = *(const short8*)&Wg[(size_t)j * 16 * w_ld + k0 + quad * 8];
            #pragma unroll
            for (int i = 0; i < 4; i++)
                #pragma unroll
                for (int j = 0; j < 3; j++)
                    acc[i][j] = __builtin_amdgcn_mfma_f32_16x16x32_bf16(af[i], bf[j], acc[i][j], 0, 0, 0);
        }
        {   // K-tail 128..143: quads 2,3 supply zeros
            bool tl = (quad < 2);
            short8 af[4], bf[3];
            #pragma unroll
            for (int i = 0; i < 4; i++)
                af[i] = tl ? *(const short8*)&As[(i * 16 + mrow) * 152 + 128 + quad * 8] : z8;
            #pragma unroll
            for (int j = 0; j < 3; j++)
                bf[j] = tl ? *(const short8*)&Wg[(size_t)j * 16 * w_ld + 128 + quad * 8] : z8;
            #pragma unroll
            for (int i = 0; i < 4; i++)
                #pragma unroll
                for (int j = 0; j < 3; j++)
                    acc[i][j] = __builtin_amdgcn_mfma_f32_16x16x32_bf16(af[i], bf[j], acc[i][j], 0, 0, 0);
        }
    }

    if constexpr (EPI == 6) {
        // write-combine through As: park 64x144 bf16 tile, then 6 contiguous 3KB head-runs
        __syncthreads();
        int slot = blockIdx.x;
        #pragma unroll
        for (int i = 0; i < 4; i++)
            #pragma unroll
            for (int reg = 0; reg < 4; reg++) {
                int ml = i * 16 + quad * 4 + reg;
                #pragma unroll
                for (int j = 0; j < 3; j++) {
                    int hn = wv3 * 48 + j * 16 + mrow;
                    float v = acc[i][j][reg];
                    if (ADDBIAS) v += bias[n0 + hn];
                    if (slot == 0) v *= 0.20412414523193154f;  // q pre-scale
                    As[ml * 152 + hn] = f2bf(v);
                }
            }
        __syncthreads();
        int chtok = o_ld;
        u32* outw = (u32*)outb;
        for (int gi = tid; gi < 4608; gi += 192) {
            int hh = gi / 768;
            int rem = gi - hh * 768;
            int t = rem / 12, dd2 = rem - t * 12;
            outw[(size_t)slot * 72 * chtok + ((size_t)hh * chtok + m0 + t) * 12 + dd2]
                = *(const u32*)&As[t * 152 + hh * 24 + dd2 * 2];
        }
    } else {
        // generic epilogue. C/D layout: col = lane&15 (n), row = quad*4 + reg (m)
        #pragma unroll
        for (int i = 0; i < 4; i++) {
            #pragma unroll
            for (int reg = 0; reg < 4; reg++) {
                int m = m0 + i * 16 + quad * 4 + reg;
                int orow;
                if (EPI == 2 || EPI == 5) {
                    int b, d, h, w;
                    win_to_src(m, SHIFTED, b, d, h, w);
                    orow = ((b * 6 + d) * 96 + h) * 96 + w;
                } else orow = m + o_add;
                #pragma unroll
                for (int j = 0; j < 3; j++) {
                    int n = n0 + wv3 * 48 + j * 16 + mrow;
                    float v = acc[i][j][reg];
                    if (ADDBIAS) v += bias[n];
                    if (EPI == 1) v = 0.5f * v * (1.f + erff(v * 0.70710678118f));
                    if (EPI == 2 || EPI == 3) {
                        fres[(size_t)orow * 144 + n] += v;
                    } else if (EPI == 5) {
                        fres[(size_t)orow * 144 + n] = y0[(size_t)orow * 144 + n] + v;
                    } else {
                        if (EPI == 4) v += y0[(size_t)orow * o_ld + n];
                        outb[(size_t)orow * o_ld + n] = f2bf(v);
                    }
                }
            }
        }
    }
}

// ---------------- window attention via MFMA: block=(win,head), 4 waves, 32-query strip per wave ----------------
// qkv layout [slot][head][chtok][24] (q pre-scaled). Swapped QK^T -> in-lane softmax (no-max,
// bounded logits), cvt_pk bf16 P. Vt/Pb stride-128 rows, XOR swizzle both sides.
// Output head-major into the chunk's tok region: [head][chtok][24].
template<int SHIFTED>
__global__ __launch_bounds__(256) void attn_mfma(
    const u16* __restrict__ qkv,        // chunk-local, [slot][head][chtok][24]
    const float* __restrict__ bexp,     // layer's expanded bias [6][128][128]
    u16* __restrict__ tok_out,          // chunk base of tok region
    int win_base, int chtok)
{
    int win = blockIdx.x;
    int head = blockIdx.y;
    __shared__ __align__(16) u16 Pb[4][2048];      // per-wave P strip [16 rows][128], swizzled
    __shared__ __align__(16) u16 Vt[3072];         // V transposed [24 d-rows][128 tok], swizzled
    __shared__ float invden_s[128];
    __shared__ u32 reg_pack[32];

    int tid = threadIdx.x;
    int wv = tid >> 6, lane = tid & 63;
    int c = lane & 15, quad = lane >> 4;
    int qbase = wv * 32;
    const short8 z8 = {0, 0, 0, 0, 0, 0, 0, 0};
    const float* bh_ = bexp + head * 16384;
    const u16* qb_ = qkv + ((size_t)head * chtok + (size_t)win * 128) * 24;
    const u16* kb_ = qb_ + (size_t)144 * chtok;
    const u16* vb_ = qb_ + (size_t)288 * chtok;
    int cs = (c & 7) << 3;

    int wdn = 0, whn = 0, wwn = 0;
    if (SHIFTED) {
        int wib = (win_base + win) % 432;
        wwn = wib % 12; whn = (wib / 12) % 12; wdn = wib / 144;
    }

    // ---- stage V transposed + swizzled, packed mask regions ----
    if (tid < 128) {
        const u32* vsrc = (const u32*)(vb_ + (size_t)tid * 24);
        #pragma unroll
        for (int i = 0; i < 12; i++) {
            u32 u = vsrc[i];
            int d0 = 2 * i, d1 = 2 * i + 1;
            Vt[((d0 << 7) + tid) ^ ((d0 & 7) << 3)] = (u16)(u & 0xffffu);
            Vt[((d1 << 7) + tid) ^ ((d1 & 7) << 3)] = (u16)(u >> 16);
        }
    }
    if (SHIFTED && tid < 32) {
        int t0 = tid * 4;
        reg_pack[tid] = (u32)tok_region(t0, wdn, whn, wwn)
                      | ((u32)tok_region(t0 + 1, wdn, whn, wwn) << 8)
                      | ((u32)tok_region(t0 + 2, wdn, whn, wwn) << 16)
                      | ((u32)tok_region(t0 + 3, wdn, whn, wwn) << 24);
    }
    __syncthreads();

    // ---- Q fragments (B-operand): rows qbase + i*16 + c ----
    short8 aq[2];
    #pragma unroll
    for (int i = 0; i < 2; i++) {
        aq[i] = z8;
        if (quad < 3)
            aq[i] = *(const short8*)(qb_ + (size_t)(qbase + i * 16 + c) * 24 + quad * 8);
    }

    // ---- S^T = K Q^T (swapped operands): lane holds S[q=i*16+c][k=j*16+quad*4+r] ----
    float4v s_acc[2][8];
    #pragma unroll
    for (int i = 0; i < 2; i++)
        #pragma unroll
        for (int j = 0; j < 8; j++) s_acc[i][j] = (float4v){0.f, 0.f, 0.f, 0.f};

    #pragma unroll
    for (int j = 0; j < 8; j++) {
        short8 kf = z8;
        if (quad < 3)
            kf = *(const short8*)(kb_ + (size_t)(j * 16 + c) * 24 + quad * 8);
        s_acc[0][j] = __builtin_amdgcn_mfma_f32_16x16x32_bf16(kf, aq[0], s_acc[0][j], 0, 0, 0);
        s_acc[1][j] = __builtin_amdgcn_mfma_f32_16x16x32_bf16(kf, aq[1], s_acc[1][j], 0, 0, 0);
    }

    float4v o_acc[2][2];
    #pragma unroll
    for (int i = 0; i < 2; i++)
        #pragma unroll
        for (int jv = 0; jv < 2; jv++) o_acc[i][jv] = (float4v){0.f, 0.f, 0.f, 0.f};

    // ---- per 16-query half: no-max softmax (in-lane) -> P(bf16, swizzled LDS) -> PV MFMA ----
    #pragma unroll
    for (int i = 0; i < 2; i++) {
        int m = qbase + i * 16 + c;
        const float* brow = bh_ + m * 128;
        u32 myreg = SHIFTED ? (u32)tok_region(m, wdn, whn, wwn) : 0u;
        float den = 0.f;
        #pragma unroll
        for (int j = 0; j < 8; j++) {
            float4 bv = *(const float4*)(brow + j * 16 + quad * 4);
            float s0 = s_acc[i][j][0] + bv.x;
            float s1 = s_acc[i][j][1] + bv.y;
            float s2 = s_acc[i][j][2] + bv.z;
            float s3 = s_acc[i][j][3] + bv.w;
            if (SHIFTED) {
                u32 rv = reg_pack[j * 4 + quad];
                s0 += ((rv & 255u) == myreg) ? 0.f : -100.f;
                s1 += (((rv >> 8) & 255u) == myreg) ? 0.f : -100.f;
                s2 += (((rv >> 16) & 255u) == myreg) ? 0.f : -100.f;
                s3 += ((rv >> 24) == myreg) ? 0.f : -100.f;
            }
            float p0 = __expf(s0), p1 = __expf(s1), p2 = __expf(s2), p3 = __expf(s3);
            den += (p0 + p1) + (p2 + p3);
            u32 w0, w1;
            asm("v_cvt_pk_bf16_f32 %0, %1, %2" : "=v"(w0) : "v"(p0), "v"(p1));
            asm("v_cvt_pk_bf16_f32 %0, %1, %2" : "=v"(w1) : "v"(p2), "v"(p3));
            uint2 wpair = make_uint2(w0, w1);
            *(uint2*)&Pb[wv][((c << 7) + j * 16 + quad * 4) ^ cs] = wpair;
        }
        den += __shfl_xor(den, 16, 64);
        den += __shfl_xor(den, 32, 64);
        if (quad == 0) invden_s[m] = 1.f / den;

        #pragma unroll
        for (int ks = 0; ks < 4; ks++) {
            short8 pf  = *(const short8*)&Pb[wv][((c << 7) + ks * 32 + quad * 8) ^ cs];
            short8 vf0 = *(const short8*)&Vt[((c << 7) + ks * 32 + quad * 8) ^ cs];
            short8 vf1 = (c < 8) ? *(const short8*)&Vt[(((16 + c) << 7) + ks * 32 + quad * 8) ^ cs] : z8;
            o_acc[i][0] = __builtin_amdgcn_mfma_f32_16x16x32_bf16(pf, vf0, o_acc[i][0], 0, 0, 0);
            o_acc[i][1] = __builtin_amdgcn_mfma_f32_16x16x32_bf16(pf, vf1, o_acc[i][1], 0, 0, 0);
        }
    }

    // ---- park O (f32) in the wave's P region for coalesced write-out ----
    float* ob = (float*)&Pb[wv][0];                // [32][26] f32 = 3328 B <= 4096 B
    #pragma unroll
    for (int i = 0; i < 2; i++)
        #pragma unroll
        for (int jv = 0; jv < 2; jv++) {
            int d = jv * 16 + c;
            if (d < 24) {
                #pragma unroll
                for (int r = 0; r < 4; r++)
                    ob[(i * 16 + quad * 4 + r) * 26 + d] = o_acc[i][jv][r];
            }
        }
    __syncthreads();

    if (tid < 128) {
        const float2* ol = (const float2*)((const float*)&Pb[0][0]
                                           + (tid >> 5) * 1024 + (tid & 31) * 26);
        float inv = invden_s[tid];
        // head-major chunk-local output: [head][chtok][24]
        u32* orow = (u32*)tok_out + ((size_t)head * chtok + (size_t)win * 128 + tid) * 12;
        #pragma unroll
        for (int d2 = 0; d2 < 12; d2++) {
            float2 v = ol[d2];
            orow[d2] = pack2(v.x * inv, v.y * inv);
        }
    }
}

// ---------------- final LN + transpose to (b, d, c, h, w), f32 out ----------------
__global__ __launch_bounds__(256) void final_ln_out_kernel(
    const u16* __restrict__ gsrc, const float* __restrict__ g, const float* __restrict__ bt,
    float* __restrict__ out)
{
    int bh = blockIdx.x;
    int h = bh % 96, d = (bh / 96) % 6, b = bh / 576;
    __shared__ u16 tile[96][152];
    __shared__ float stat[96][2];
    const u16* src = gsrc + (size_t)bh * 96 * 144;
    for (int i = threadIdx.x; i < 1728; i += 256) {
        int wt = i / 18, c8 = i - wt * 18;
        *(short8*)&tile[wt][c8 * 8] = *(const short8*)&src[wt * 144 + c8 * 8];
    }
    __syncthreads();
    if (threadIdx.x < 96) {
        const u32* row = (const u32*)&tile[threadIdx.x][0];
        float s = 0.f, s2 = 0.f;
        #pragma unroll
        for (int j = 0; j < 72; j++) {
            float lo, hi; unpack2(row[j], lo, hi);
            s += lo + hi; s2 += lo * lo + hi * hi;
        }
        float mu = s * (1.f / 144.f);
        float var = s2 * (1.f / 144.f) - mu * mu;
        stat[threadIdx.x][0] = mu;
        stat[threadIdx.x][1] = rsqrtf(fmaxf(var, 0.f) + 1e-5f);
    }
    __syncthreads();
    size_t obase = ((size_t)(b * 6 + d) * 144) * 9216 + h * 96;
    for (int i = threadIdx.x; i < 96 * 144; i += blockDim.x) {
        int c = i / 96, wt = i - c * 96;
        out[obase + (size_t)c * 9216 + wt] =
            (bf2f(tile[wt][c]) - stat[wt][0]) * stat[wt][1] * g[c] + bt[c];
    }
}

extern "C" void kernel_launch(void* const* d_in, const int* in_sizes, int n_in,
                              void* d_out, int out_size, void* d_ws, size_t ws_size,
                              hipStream_t stream) {
    const float* x     = (const float*)d_in[0];
    const float* convw = (const float*)d_in[1];
    const float* convb = (const float*)d_in[2];
    const float* ln0g  = (const float*)d_in[3];
    const float* ln0b  = (const float*)d_in[4];
    const float* n1g   = (const float*)d_in[5];
    const float* n1b   = (const float*)d_in[6];
    const float* qkvw  = (const float*)d_in[7];
    const float* qkvb  = (const float*)d_in[8];
    const float* rpb   = (const float*)d_in[9];
    const float* projw = (const float*)d_in[10];
    const float* projb = (const float*)d_in[11];
    const float* n2g   = (const float*)d_in[12];
    const float* n2b   = (const float*)d_in[13];
    const float* fc1w  = (const float*)d_in[14];
    const float* fc1b  = (const float*)d_in[15];
    const float* fc2w  = (const float*)d_in[16];
    const float* fc2b  = (const float*)d_in[17];
    const float* linw  = (const float*)d_in[18];
    const float* linb  = (const float*)d_in[19];
    const float* ln1g  = (const float*)d_in[20];
    const float* ln1b  = (const float*)d_in[21];

    // ws layout: f fp32 | tok bf16 | wbuf | bexp | qkvbuf (rest; sized by ws_size)
    char* wp = (char*)d_ws;
    float* f    = (float*)wp;             wp += (size_t)TS * 4;
    u16*   tok  = (u16*)wp;               wp += (size_t)TS * 2;
    u16*   wbuf = (u16*)wp;               wp += 352512ull * 2;
    float* bexp = (float*)wp;             wp += 196608ull * 4;
    u16*   qkvbuf = (u16*)wp;
    size_t rest = ws_size - (size_t)(wp - (char*)d_ws);
    int nch = (rest >= (size_t)NTOK * 432 * 2) ? 1
            : (rest >= (size_t)NTOK * 216 * 2) ? 2 : 4;
    int nm  = (rest >= (size_t)NTOK * 288 * 2) ? 1
            : (rest >= (size_t)NTOK * 144 * 2) ? 2 : 3;
    float* y0 = (float*)d_out;   // conv+LN0 output parked in d_out until the end

    convert_weights<<<2145, 256, 0, stream>>>(qkvw, projw, fc1w, fc2w, linw, wbuf, rpb, bexp);
    conv_ln0_row<<<1152, 256, 0, stream>>>(x, convw, convb, ln0g, ln0b, y0);

    for (int layer = 0; layer < 2; ++layer) {
        const u16* qw  = wbuf + (size_t)layer * 62208;
        const u16* pw  = wbuf + 124416 + (size_t)layer * 20736;
        const u16* f1w = wbuf + 165888 + (size_t)layer * 41472;
        const u16* f2w = wbuf + 248832 + (size_t)layer * 41472;
        const float* qb  = qkvb + (size_t)layer * 432;
        const float* pb  = projb + (size_t)layer * 144;
        const float* g1  = n1g + layer * 144;
        const float* b1  = n1b + layer * 144;
        const float* g2  = n2g + layer * 144;
        const float* b2  = n2b + layer * 144;
        const float* f1b = fc1b + (size_t)layer * 288;
        const float* f2b = fc2b + (size_t)layer * 144;
        const float* bx  = bexp + (size_t)layer * 98304;

        // LN1 + roll + window partition -> tok (windowed bf16 rows)
        if (layer == 0) ln_gather<1><<<NTOK / 4, 256, 0, stream>>>(y0, tok, g1, b1);
        else            ln_gather<2><<<NTOK / 4, 256, 0, stream>>>(f, tok, g1, b1);

        // attention in nch token chunks; attn output overwrites its chunk's tok region
        int chtok = NTOK / nch, chwin = NWIN / nch;
        for (int c = 0; c < nch; c++) {
            mgemm<2, 6, 0, 1, 1><<<dim3(3, chtok / 64), 192, 0, stream>>>(
                tok, qw, qb, qkvbuf, nullptr, nullptr, nullptr, nullptr,
                c * chtok, 144, 144, chtok, 0);
            u16* ob = tok + (size_t)c * chtok * 144;
            if (layer == 0)
                attn_mfma<0><<<dim3(chwin, 6), 256, 0, stream>>>(qkvbuf, bx, ob, c * chwin, chtok);
            else
                attn_mfma<1><<<dim3(chwin, 6), 256, 0, stream>>>(qkvbuf, bx, ob, c * chwin, chtok);
        }

        // proj (AMODE 3: chunked head-major A) + window-reverse scatter into f
        if (layer == 0)
            mgemm<3, 5, 0, 1, 1><<<dim3(1, NTOK / 64), 192, 0, stream>>>(
                tok, pw, pb, nullptr, f, y0, nullptr, nullptr, 0, chtok, 144, 144, 0);
        else
            mgemm<3, 2, 1, 1, 1><<<dim3(1, NTOK / 64), 192, 0, stream>>>(
                tok, pw, pb, nullptr, f, nullptr, nullptr, nullptr, 0, chtok, 144, 144, 0);

        // MLP in nm chunks (hidden lives in qkvbuf: fcch x 288 bf16)
        // LN2 fused into fc1's A-staging (AMODE 5, reads f fp32 directly)
        int fcch = NTOK / nm;
        for (int c = 0; c < nm; c++) {
            int mst = c * fcch;
            mgemm<5, 1, 0, 1, 1><<<dim3(2, fcch / 64), 192, 0, stream>>>(
                f, f1w, f1b, qkvbuf, nullptr, nullptr, g2, b2, mst, 144, 144, 288, 0);
            mgemm<2, 3, 0, 1, 2><<<dim3(1, fcch / 64), 192, 0, stream>>>(
                qkvbuf, f2w, f2b, nullptr, f, nullptr, nullptr, nullptr, 0, 288, 288, 144, mst);
        }
    }

    // final linear + conv-residual y0 -> tok (bf16, spatial rows)
    mgemm<0, 4, 0, 1, 1><<<dim3(1, NTOK / 64), 192, 0, stream>>>(
        f, wbuf + 331776, linb, tok, nullptr, y0, nullptr, nullptr, 0, 144, 144, 144, 0);

    // trailing LN + transpose to (n, d, c, h, w), fp32 out
    final_ln_out_kernel<<<2 * 6 * 96, 256, 0, stream>>>(tok, ln1g, ln1b, (float*)d_out);
}

// Round 12
// 754.432 us; speedup vs baseline: 1.2060x; 1.0466x over previous
//
#include <hip/hip_runtime.h>
#include <math.h>

#define NTOK 110592      // B*D*H*W = 2*6*96*96
#define NWIN 864         // 2 * 3 * 12 * 12
#define TS   15925248    // NTOK*144

typedef unsigned short u16;
typedef unsigned int   u32;
typedef __attribute__((ext_vector_type(8))) short short8;
typedef __attribute__((ext_vector_type(4))) float float4v;

__device__ __forceinline__ float bf2f(u16 v) { return __uint_as_float(((u32)v) << 16); }
__device__ __forceinline__ u16 f2bf(float f) {
    u32 u = __float_as_uint(f);
    u32 r = u + 0x7fffu + ((u >> 16) & 1u);
    return (u16)(r >> 16);
}
__device__ __forceinline__ void unpack2(u32 u, float& lo, float& hi) {
    lo = __uint_as_float(u << 16);
    hi = __uint_as_float(u & 0xffff0000u);
}
__device__ __forceinline__ u32 pack2(float lo, float hi) {
    return (u32)f2bf(lo) | ((u32)f2bf(hi) << 16);
}
__device__ __forceinline__ float wave_sum(float v) {
    #pragma unroll
    for (int o = 32; o > 0; o >>= 1) v += __shfl_xor(v, o, 64);
    return v;
}
__device__ __forceinline__ float fexp2(float x) {
    float r;
    asm("v_exp_f32 %0, %1" : "=v"(r) : "v"(x));
    return r;
}

// windowed token index -> source spatial coords (handles roll for shifted layers)
__device__ __forceinline__ void win_to_src(int tw, int shifted, int& sb, int& sd, int& sh, int& sw) {
    int n = tw & 127;
    int win = tw >> 7;
    int ww = win % 12;
    int wh = (win / 12) % 12;
    int rest = win / 144;
    int wd = rest % 3;
    sb = rest / 3;
    int ld = n >> 6, lh = (n >> 3) & 7, lw = n & 7;
    int dr = wd * 2 + ld, hr = wh * 8 + lh, wr = ww * 8 + lw;
    if (shifted) {
        sd = (dr + 1) % 6;
        sh = (hr + 4) % 96;
        sw = (wr + 4) % 96;
    } else {
        sd = dr; sh = hr; sw = wr;
    }
}

// region id of window-local token t for the shifted-window mask
__device__ __forceinline__ int tok_region(int t, int wdn, int whn, int wwn) {
    int dr = wdn * 2 + (t >> 6), hr = whn * 8 + ((t >> 3) & 7), wr = wwn * 8 + (t & 7);
    int rd = (dr < 4) ? 0 : ((dr < 5) ? 1 : 2);
    int rh = (hr < 88) ? 0 : ((hr < 92) ? 1 : 2);
    int rw = (wr < 88) ? 0 : ((wr < 92) ? 1 : 2);
    return rd * 9 + rh * 3 + rw;
}

// ---------------- weight pre-conversion fp32 -> bf16 + bias-table expansion ----------------
// bexp scaled by log2(e): attention uses exp2 directly.
__global__ __launch_bounds__(256) void convert_weights(
    const float* __restrict__ qkvw, const float* __restrict__ projw,
    const float* __restrict__ fc1w, const float* __restrict__ fc2w,
    const float* __restrict__ linw, u16* __restrict__ wbuf,
    const float* __restrict__ rpb, float* __restrict__ bexp)
{
    int i = blockIdx.x * 256 + threadIdx.x;
    if (i < 124416) wbuf[i] = f2bf(qkvw[i]);
    else if (i < 165888) wbuf[i] = f2bf(projw[i - 124416]);
    else if (i < 248832) wbuf[i] = f2bf(fc1w[i - 165888]);
    else if (i < 331776) wbuf[i] = f2bf(fc2w[i - 248832]);
    else if (i < 352512) wbuf[i] = f2bf(linw[i - 331776]);
    else if (i < 549120) {
        int k = i - 352512;
        int n = k & 127, m = (k >> 7) & 127;
        int lh = k >> 14;
        int h = lh % 6, l = lh / 6;
        int rdi = (m >> 6) - (n >> 6) + 1;
        int rhi = ((m >> 3) & 7) - ((n >> 3) & 7) + 7;
        int rwi = (m & 7) - (n & 7) + 7;
        int bi = (rdi * 15 + rhi) * 15 + rwi;
        bexp[k] = rpb[l * 4050 + bi * 6 + h] * 1.4426950408889634f;
    }
}

// ---------------- conv3d(1x3x3) + bias + LN0, block = (b,d,h) row of 96 positions ----------------
__global__ __launch_bounds__(256) void conv_ln0_row(
    const float* __restrict__ x, const float* __restrict__ cw, const float* __restrict__ cb,
    const float* __restrict__ g0, const float* __restrict__ b0,
    float* __restrict__ y0)
{
    int bh = blockIdx.x;                 // (b*6+d)*96 + h
    int h = bh % 96, bd = bh / 96;
    int b = bd / 6, d = bd - b * 6;
    __shared__ float ws[192][29];
    __shared__ float xsr[9][100];
    __shared__ float cbias[192], gg[144], bbv[144];
    int tid = threadIdx.x;

    for (int i = tid; i < 9 * 98; i += 256) {
        int row = i / 98, wx = i - row * 98;
        int ci = row / 3, kh = row - 3 * ci;
        int hh = h + kh - 1, wsrc = wx - 1;
        float v = 0.f;
        if (hh >= 0 && hh < 96 && wsrc >= 0 && wsrc < 96)
            v = x[((((size_t)b * 6 + d) * 3 + ci) * 96 + hh) * 96 + wsrc];
        xsr[row][wx] = v;
    }
    for (int i = tid; i < 192 * 27; i += 256) {
        int c = i / 27, j = i - c * 27;
        ws[c][j] = (c < 144) ? cw[c * 27 + j] : 0.f;
    }
    for (int i = tid; i < 192; i += 256) cbias[i] = (i < 144) ? cb[i] : 0.f;
    for (int i = tid; i < 144; i += 256) { gg[i] = g0[i]; bbv[i] = b0[i]; }
    __syncthreads();

    int wv = tid >> 6, lane = tid & 63;
    int p0 = wv * 24;

    float a0[24], a1[24], a2[24];
    #pragma unroll
    for (int k = 0; k < 24; k++) {
        a0[k] = cbias[lane]; a1[k] = cbias[lane + 64]; a2[k] = cbias[lane + 128];
    }

    for (int cikh = 0; cikh < 9; cikh++) {
        const float* xr = &xsr[cikh][p0];
        float xv[26];
        #pragma unroll
        for (int t = 0; t < 26; t++) xv[t] = xr[t];
        #pragma unroll
        for (int kw = 0; kw < 3; kw++) {
            int j = cikh * 3 + kw;
            float w0 = ws[lane][j], w1 = ws[lane + 64][j], w2 = ws[lane + 128][j];
            #pragma unroll
            for (int k = 0; k < 24; k++) {
                float xvv = xv[k + kw];
                a0[k] += w0 * xvv; a1[k] += w1 * xvv; a2[k] += w2 * xvv;
            }
        }
    }

    #pragma unroll
    for (int k = 0; k < 24; k++) {
        int p = p0 + k;
        float v0 = a0[k], v1 = a1[k];
        float v2m = (lane < 16) ? a2[k] : 0.f;
        float s  = wave_sum(v0 + v1 + v2m);
        float s2 = wave_sum(v0 * v0 + v1 * v1 + v2m * v2m);
        float mu = s * (1.f / 144.f);
        float rstd = rsqrtf(fmaxf(s2 * (1.f / 144.f) - mu * mu, 0.f) + 1e-5f);
        size_t o = ((size_t)bh * 96 + p) * 144;
        float r0 = (v0 - mu) * rstd * gg[lane] + bbv[lane];
        float r1 = (v1 - mu) * rstd * gg[lane + 64] + bbv[lane + 64];
        y0[o + lane] = r0;
        y0[o + lane + 64] = r1;
        if (lane < 16) {
            float r2 = (a2[k] - mu) * rstd * gg[lane + 128] + bbv[lane + 128];
            y0[o + lane + 128] = r2;
        }
    }
}

// ---------------- MFMA GEMM: C[M,N] = A[M,144*KTILES] @ W^T (+bias), tile 64x144, 192 thr ----------------
// AMODE: 0 fp32 A rows; 2 bf16 A rows; 3 bf16 chunked head-major A (attn out; a_ld = chunk tokens);
//        5 fp32 A rows + fused LayerNorm; 6 fp32 A rows + fused LN + windowed gather (SHIFTED roll).
// EPI: 0 store bf16; 1 gelu->bf16; 2 scatter-add f32 (win_to_src); 3 add f32; 4 (y0+v)->bf16;
//      5 scatter f32 = y0[orow] + v (win_to_src);
//      6 qkv store, write-combined via LDS: layout [slot][head][chtok][24], slot=blockIdx.x,
//        q pre-scaled by 1/sqrt(24)*log2(e) (o_ld = chunk tokens).
template<int AMODE, int EPI, int SHIFTED, int ADDBIAS, int KTILES>
__global__ __launch_bounds__(192) void mgemm(
    const void* __restrict__ Asrc, const u16* __restrict__ Wt, const float* __restrict__ bias,
    u16* __restrict__ outb, float* __restrict__ fres, const float* __restrict__ y0,
    const float* __restrict__ lng, const float* __restrict__ lnb,
    int a_add, int a_ld, int w_ld, int o_ld, int o_add)
{
    __shared__ u16 As[64 * 152];
    int m0 = blockIdx.y * 64, n0 = blockIdx.x * 144;
    int tid = threadIdx.x;
    int wv3 = tid / 64, lane = tid & 63;
    int mrow = lane & 15, quad = lane >> 4;
    const short8 z8 = {0, 0, 0, 0, 0, 0, 0, 0};

    float4v acc[4][3];
    #pragma unroll
    for (int i = 0; i < 4; i++)
        #pragma unroll
        for (int j = 0; j < 3; j++) acc[i][j] = (float4v){0.f, 0.f, 0.f, 0.f};

    #pragma unroll
    for (int kt = 0; kt < KTILES; kt++) {
        if (kt) __syncthreads();
        if constexpr (AMODE == 5 || AMODE == 6) {
            // fused-LN staging: 3 threads per row, partial sums via LDS exchange
            __shared__ float gs[144], bs[144], ps[64][6];
            for (int i = tid; i < 144; i += 192) { gs[i] = lng[i]; bs[i] = lnb[i]; }
            int r = tid / 3, p = tid - 3 * r;
            int srow;
            if constexpr (AMODE == 6) {
                int bq, dq, hq, wq;
                win_to_src(a_add + m0 + r, SHIFTED, bq, dq, hq, wq);
                srow = ((bq * 6 + dq) * 96 + hq) * 96 + wq;
            } else {
                srow = a_add + m0 + r;
            }
            const float4* s4 = (const float4*)((const float*)Asrc + (size_t)srow * 144) + p * 12;
            float4 av[12];
            float s = 0.f, s2 = 0.f;
            #pragma unroll
            for (int q = 0; q < 12; q++) {
                av[q] = s4[q];
                s  += (av[q].x + av[q].y) + (av[q].z + av[q].w);
                s2 += (av[q].x * av[q].x + av[q].y * av[q].y)
                    + (av[q].z * av[q].z + av[q].w * av[q].w);
            }
            ps[r][p] = s; ps[r][3 + p] = s2;
            __syncthreads();
            float S  = ps[r][0] + ps[r][1] + ps[r][2];
            float S2 = ps[r][3] + ps[r][4] + ps[r][5];
            float mu = S * (1.f / 144.f);
            float rstd = rsqrtf(fmaxf(S2 * (1.f / 144.f) - mu * mu, 0.f) + 1e-5f);
            #pragma unroll
            for (int q = 0; q < 12; q++) {
                int n = p * 48 + q * 4;
                *(u32*)&As[r * 152 + n]     = pack2((av[q].x - mu) * rstd * gs[n]     + bs[n],
                                                    (av[q].y - mu) * rstd * gs[n + 1] + bs[n + 1]);
                *(u32*)&As[r * 152 + n + 2] = pack2((av[q].z - mu) * rstd * gs[n + 2] + bs[n + 2],
                                                    (av[q].w - mu) * rstd * gs[n + 3] + bs[n + 3]);
            }
        } else if constexpr (AMODE == 2) {
            const u16* A = (const u16*)Asrc;
            #pragma unroll
            for (int idx = tid; idx < 1152; idx += 192) {   // 64 rows x 18 chunks
                int r = idx / 18, c4 = idx - r * 18;
                *(short8*)&As[r * 152 + c4 * 8] =
                    *(const short8*)&A[(size_t)(a_add + m0 + r) * a_ld + kt * 144 + c4 * 8];
            }
        } else if constexpr (AMODE == 3) {
            // chunked head-major attn output: chunk cc, layout [6][chtok][24] inside chunk region
            const u16* A = (const u16*)Asrc;
            int chtok = a_ld;
            int cc = m0 / chtok;
            int t0 = m0 - cc * chtok;
            const u16* Ac = A + (size_t)cc * chtok * 144;
            #pragma unroll
            for (int idx = tid; idx < 1152; idx += 192) {
                int r = idx / 18, c4 = idx - r * 18;
                int hh = c4 / 3, sub = c4 - hh * 3;
                *(short8*)&As[r * 152 + c4 * 8] =
                    *(const short8*)&Ac[((size_t)hh * chtok + t0 + r) * 24 + sub * 8];
            }
        } else {
            const float* A = (const float*)Asrc;
            #pragma unroll
            for (int idx = tid; idx < 2304; idx += 192) {   // 64 rows x 36 float4
                int r = idx / 36, c4 = idx - r * 36;
                const float4* src4 = (const float4*)&A[(size_t)(a_add + m0 + r) * a_ld + kt * 144];
                float4 v = src4[c4];
                *(u32*)&As[r * 152 + c4 * 4]     = pack2(v.x, v.y);
                *(u32*)&As[r * 152 + c4 * 4 + 2] = pack2(v.z, v.w);
            }
        }
        __syncthreads();

        const u16* Wg = Wt + (size_t)(n0 + wv3 * 48 + mrow) * w_ld + kt * 144;

        #pragma unroll
        for (int ks = 0; ks < 4; ks++) {
            int k0 = ks * 32;
            short8 af[4], bf[3];
            #pragma unroll
            for (int i = 0; i < 4; i++)
                af[i] = *(const short8*)&As[(i * 16 + mrow) * 152 + k0 + quad * 8];
            #pragma unroll
            for (int j = 0; j < 3; j++)
                bf[j] = *(const short8*)&Wg[(size_t)j * 16 * w_ld + k0 + quad * 8];
            #pragma unroll
            for (int i = 0; i < 4; i++)
                #pragma unroll
                for (int j = 0; j < 3; j++)
                    acc[i][j] = __builtin_amdgcn_mfma_f32_16x16x32_bf16(af[i], bf[j], acc[i][j], 0, 0, 0);
        }
        {   // K-tail 128..143: quads 2,3 supply zeros
            bool tl = (quad < 2);
            short8 af[4], bf[3];
            #pragma unroll
            for (int i = 0; i < 4; i++)
                af[i] = tl ? *(const short8*)&As[(i * 16 + mrow) * 152 + 128 + quad * 8] : z8;
            #pragma unroll
            for (int j = 0; j < 3; j++)
                bf[j] = tl ? *(const short8*)&Wg[(size_t)j * 16 * w_ld + 128 + quad * 8] : z8;
            #pragma unroll
            for (int i = 0; i < 4; i++)
                #pragma unroll
                for (int j = 0; j < 3; j++)
                    acc[i][j] = __builtin_amdgcn_mfma_f32_16x16x32_bf16(af[i], bf[j], acc[i][j], 0, 0, 0);
        }
    }

    if constexpr (EPI == 6) {
        // write-combine through As: park 64x144 bf16 tile, then 6 contiguous 3KB head-runs
        __syncthreads();
        int slot = blockIdx.x;
        #pragma unroll
        for (int i = 0; i < 4; i++)
            #pragma unroll
            for (int reg = 0; reg < 4; reg++) {
                int ml = i * 16 + quad * 4 + reg;
                #pragma unroll
                for (int j = 0; j < 3; j++) {
                    int hn = wv3 * 48 + j * 16 + mrow;
                    float v = acc[i][j][reg];
                    if (ADDBIAS) v += bias[n0 + hn];
                    if (slot == 0) v *= 0.29448890f;  // 1/sqrt(24) * log2(e)
                    As[ml * 152 + hn] = f2bf(v);
                }
            }
        __syncthreads();
        int chtok = o_ld;
        u32* outw = (u32*)outb;
        for (int gi = tid; gi < 4608; gi += 192) {
            int hh = gi / 768;
            int rem = gi - hh * 768;
            int t = rem / 12, dd2 = rem - t * 12;
            outw[(size_t)slot * 72 * chtok + ((size_t)hh * chtok + m0 + t) * 12 + dd2]
                = *(const u32*)&As[t * 152 + hh * 24 + dd2 * 2];
        }
    } else {
        // generic epilogue. C/D layout: col = lane&15 (n), row = quad*4 + reg (m)
        #pragma unroll
        for (int i = 0; i < 4; i++) {
            #pragma unroll
            for (int reg = 0; reg < 4; reg++) {
                int m = m0 + i * 16 + quad * 4 + reg;
                int orow;
                if (EPI == 2 || EPI == 5) {
                    int b, d, h, w;
                    win_to_src(m, SHIFTED, b, d, h, w);
                    orow = ((b * 6 + d) * 96 + h) * 96 + w;
                } else orow = m + o_add;
                #pragma unroll
                for (int j = 0; j < 3; j++) {
                    int n = n0 + wv3 * 48 + j * 16 + mrow;
                    float v = acc[i][j][reg];
                    if (ADDBIAS) v += bias[n];
                    if (EPI == 1) v = 0.5f * v * (1.f + erff(v * 0.70710678118f));
                    if (EPI == 2 || EPI == 3) {
                        fres[(size_t)orow * 144 + n] += v;
                    } else if (EPI == 5) {
                        fres[(size_t)orow * 144 + n] = y0[(size_t)orow * 144 + n] + v;
                    } else {
                        if (EPI == 4) v += y0[(size_t)orow * o_ld + n];
                        outb[(size_t)orow * o_ld + n] = f2bf(v);
                    }
                }
            }
        }
    }
}

// ---------------- window attention via MFMA: block=(win,head), 4 waves, 32-query strip per wave ----------------
// qkv layout [slot][head][chtok][24] (q pre-scaled incl. log2e). Swapped QK^T -> in-lane softmax
// via exp2 (no-max, bounded logits), cvt_pk bf16 P. Vt/Pb stride-128 rows, XOR swizzle both sides.
// Bias prefetched into registers (half-0 before QK MFMA, half-1 during half-0's PV).
// Output head-major into the chunk's tok region: [head][chtok][24].
template<int SHIFTED>
__global__ __launch_bounds__(256) void attn_mfma(
    const u16* __restrict__ qkv,        // chunk-local, [slot][head][chtok][24]
    const float* __restrict__ bexp,     // layer's expanded bias [6][128][128], pre-scaled by log2e
    u16* __restrict__ tok_out,          // chunk base of tok region
    int win_base, int chtok)
{
    int win = blockIdx.x;
    int head = blockIdx.y;
    __shared__ __align__(16) u16 Pb[4][2048];      // per-wave P strip [16 rows][128], swizzled
    __shared__ __align__(16) u16 Vt[3072];         // V transposed [24 d-rows][128 tok], swizzled
    __shared__ float invden_s[128];
    __shared__ u32 reg_pack[32];

    int tid = threadIdx.x;
    int wv = tid >> 6, lane = tid & 63;
    int c = lane & 15, quad = lane >> 4;
    int qbase = wv * 32;
    const short8 z8 = {0, 0, 0, 0, 0, 0, 0, 0};
    const float* bh_ = bexp + head * 16384;
    const u16* qb_ = qkv + ((size_t)head * chtok + (size_t)win * 128) * 24;
    const u16* kb_ = qb_ + (size_t)144 * chtok;
    const u16* vb_ = qb_ + (size_t)288 * chtok;
    int cs = (c & 7) << 3;

    int wdn = 0, whn = 0, wwn = 0;
    if (SHIFTED) {
        int wib = (win_base + win) % 432;
        wwn = wib % 12; whn = (wib / 12) % 12; wdn = wib / 144;
    }

    // ---- stage V transposed + swizzled, packed mask regions ----
    if (tid < 128) {
        const u32* vsrc = (const u32*)(vb_ + (size_t)tid * 24);
        #pragma unroll
        for (int i = 0; i < 12; i++) {
            u32 u = vsrc[i];
            int d0 = 2 * i, d1 = 2 * i + 1;
            Vt[((d0 << 7) + tid) ^ ((d0 & 7) << 3)] = (u16)(u & 0xffffu);
            Vt[((d1 << 7) + tid) ^ ((d1 & 7) << 3)] = (u16)(u >> 16);
        }
    }
    if (SHIFTED && tid < 32) {
        int t0 = tid * 4;
        reg_pack[tid] = (u32)tok_region(t0, wdn, whn, wwn)
                      | ((u32)tok_region(t0 + 1, wdn, whn, wwn) << 8)
                      | ((u32)tok_region(t0 + 2, wdn, whn, wwn) << 16)
                      | ((u32)tok_region(t0 + 3, wdn, whn, wwn) << 24);
    }
    __syncthreads();

    // ---- Q fragments (B-operand): rows qbase + i*16 + c ----
    short8 aq[2];
    #pragma unroll
    for (int i = 0; i < 2; i++) {
        aq[i] = z8;
        if (quad < 3)
            aq[i] = *(const short8*)(qb_ + (size_t)(qbase + i * 16 + c) * 24 + quad * 8);
    }

    // ---- prefetch half-0 bias into registers (overlaps K loads + QK MFMA) ----
    float4 bv0[8];
    {
        const float* brow = bh_ + (qbase + c) * 128;
        #pragma unroll
        for (int j = 0; j < 8; j++)
            bv0[j] = *(const float4*)(brow + j * 16 + quad * 4);
    }

    // ---- S^T = K Q^T (swapped operands): lane holds S[q=i*16+c][k=j*16+quad*4+r] ----
    float4v s_acc[2][8];
    #pragma unroll
    for (int i = 0; i < 2; i++)
        #pragma unroll
        for (int j = 0; j < 8; j++) s_acc[i][j] = (float4v){0.f, 0.f, 0.f, 0.f};

    #pragma unroll
    for (int j = 0; j < 8; j++) {
        short8 kf = z8;
        if (quad < 3)
            kf = *(const short8*)(kb_ + (size_t)(j * 16 + c) * 24 + quad * 8);
        s_acc[0][j] = __builtin_amdgcn_mfma_f32_16x16x32_bf16(kf, aq[0], s_acc[0][j], 0, 0, 0);
        s_acc[1][j] = __builtin_amdgcn_mfma_f32_16x16x32_bf16(kf, aq[1], s_acc[1][j], 0, 0, 0);
    }

    float4v o_acc[2][2];
    #pragma unroll
    for (int i = 0; i < 2; i++)
        #pragma unroll
        for (int jv = 0; jv < 2; jv++) o_acc[i][jv] = (float4v){0.f, 0.f, 0.f, 0.f};

    u32 myreg0 = SHIFTED ? (u32)tok_region(qbase + c, wdn, whn, wwn) : 0u;
    u32 myreg1 = SHIFTED ? (u32)tok_region(qbase + 16 + c, wdn, whn, wwn) : 0u;
    float4 bv1[8];

    // ======== half 0: softmax (exp2, bias from regs) -> P -> prefetch bv1 -> PV ========
    {
        float den = 0.f;
        #pragma unroll
        for (int j = 0; j < 8; j++) {
            float s0 = s_acc[0][j][0] + bv0[j].x;
            float s1 = s_acc[0][j][1] + bv0[j].y;
            float s2 = s_acc[0][j][2] + bv0[j].z;
            float s3 = s_acc[0][j][3] + bv0[j].w;
            if (SHIFTED) {
                u32 rv = reg_pack[j * 4 + quad];
                s0 += ((rv & 255u) == myreg0) ? 0.f : -144.2695f;
                s1 += (((rv >> 8) & 255u) == myreg0) ? 0.f : -144.2695f;
                s2 += (((rv >> 16) & 255u) == myreg0) ? 0.f : -144.2695f;
                s3 += ((rv >> 24) == myreg0) ? 0.f : -144.2695f;
            }
            float p0 = fexp2(s0), p1 = fexp2(s1), p2 = fexp2(s2), p3 = fexp2(s3);
            den += (p0 + p1) + (p2 + p3);
            u32 w0, w1;
            asm("v_cvt_pk_bf16_f32 %0, %1, %2" : "=v"(w0) : "v"(p0), "v"(p1));
            asm("v_cvt_pk_bf16_f32 %0, %1, %2" : "=v"(w1) : "v"(p2), "v"(p3));
            uint2 wpair = make_uint2(w0, w1);
            *(uint2*)&Pb[wv][((c << 7) + j * 16 + quad * 4) ^ cs] = wpair;
        }
        den += __shfl_xor(den, 16, 64);
        den += __shfl_xor(den, 32, 64);
        if (quad == 0) invden_s[qbase + c] = 1.f / den;

        // prefetch half-1 bias (latency hidden under PV below)
        {
            const float* brow = bh_ + (qbase + 16 + c) * 128;
            #pragma unroll
            for (int j = 0; j < 8; j++)
                bv1[j] = *(const float4*)(brow + j * 16 + quad * 4);
        }

        #pragma unroll
        for (int ks = 0; ks < 4; ks++) {
            short8 pf  = *(const short8*)&Pb[wv][((c << 7) + ks * 32 + quad * 8) ^ cs];
            short8 vf0 = *(const short8*)&Vt[((c << 7) + ks * 32 + quad * 8) ^ cs];
            short8 vf1 = (c < 8) ? *(const short8*)&Vt[(((16 + c) << 7) + ks * 32 + quad * 8) ^ cs] : z8;
            o_acc[0][0] = __builtin_amdgcn_mfma_f32_16x16x32_bf16(pf, vf0, o_acc[0][0], 0, 0, 0);
            o_acc[0][1] = __builtin_amdgcn_mfma_f32_16x16x32_bf16(pf, vf1, o_acc[0][1], 0, 0, 0);
        }
    }

    // ======== half 1: softmax (bias from regs) -> P -> PV ========
    {
        float den = 0.f;
        #pragma unroll
        for (int j = 0; j < 8; j++) {
            float s0 = s_acc[1][j][0] + bv1[j].x;
            float s1 = s_acc[1][j][1] + bv1[j].y;
            float s2 = s_acc[1][j][2] + bv1[j].z;
            float s3 = s_acc[1][j][3] + bv1[j].w;
            if (SHIFTED) {
                u32 rv = reg_pack[j * 4 + quad];
                s0 += ((rv & 255u) == myreg1) ? 0.f : -144.2695f;
                s1 += (((rv >> 8) & 255u) == myreg1) ? 0.f : -144.2695f;
                s2 += (((rv >> 16) & 255u) == myreg1) ? 0.f : -144.2695f;
                s3 += ((rv >> 24) == myreg1) ? 0.f : -144.2695f;
            }
            float p0 = fexp2(s0), p1 = fexp2(s1), p2 = fexp2(s2), p3 = fexp2(s3);
            den += (p0 + p1) + (p2 + p3);
            u32 w0, w1;
            asm("v_cvt_pk_bf16_f32 %0, %1, %2" : "=v"(w0) : "v"(p0), "v"(p1));
            asm("v_cvt_pk_bf16_f32 %0, %1, %2" : "=v"(w1) : "v"(p2), "v"(p3));
            uint2 wpair = make_uint2(w0, w1);
            *(uint2*)&Pb[wv][((c << 7) + j * 16 + quad * 4) ^ cs] = wpair;
        }
        den += __shfl_xor(den, 16, 64);
        den += __shfl_xor(den, 32, 64);
        if (quad == 0) invden_s[qbase + 16 + c] = 1.f / den;

        #pragma unroll
        for (int ks = 0; ks < 4; ks++) {
            short8 pf  = *(const short8*)&Pb[wv][((c << 7) + ks * 32 + quad * 8) ^ cs];
            short8 vf0 = *(const short8*)&Vt[((c << 7) + ks * 32 + quad * 8) ^ cs];
            short8 vf1 = (c < 8) ? *(const short8*)&Vt[(((16 + c) << 7) + ks * 32 + quad * 8) ^ cs] : z8;
            o_acc[1][0] = __builtin_amdgcn_mfma_f32_16x16x32_bf16(pf, vf0, o_acc[1][0], 0, 0, 0);
            o_acc[1][1] = __builtin_amdgcn_mfma_f32_16x16x32_bf16(pf, vf1, o_acc[1][1], 0, 0, 0);
        }
    }

    // ---- park O (f32) in the wave's P region for coalesced write-out ----
    float* ob = (float*)&Pb[wv][0];                // [32][26] f32 = 3328 B <= 4096 B
    #pragma unroll
    for (int i = 0; i < 2; i++)
        #pragma unroll
        for (int jv = 0; jv < 2; jv++) {
            int d = jv * 16 + c;
            if (d < 24) {
                #pragma unroll
                for (int r = 0; r < 4; r++)
                    ob[(i * 16 + quad * 4 + r) * 26 + d] = o_acc[i][jv][r];
            }
        }
    __syncthreads();

    if (tid < 128) {
        const float2* ol = (const float2*)((const float*)&Pb[0][0]
                                           + (tid >> 5) * 1024 + (tid & 31) * 26);
        float inv = invden_s[tid];
        // head-major chunk-local output: [head][chtok][24]
        u32* orow = (u32*)tok_out + ((size_t)head * chtok + (size_t)win * 128 + tid) * 12;
        #pragma unroll
        for (int d2 = 0; d2 < 12; d2++) {
            float2 v = ol[d2];
            orow[d2] = pack2(v.x * inv, v.y * inv);
        }
    }
}

// ---------------- final LN + transpose to (b, d, c, h, w), f32 out ----------------
__global__ __launch_bounds__(256) void final_ln_out_kernel(
    const u16* __restrict__ gsrc, const float* __restrict__ g, const float* __restrict__ bt,
    float* __restrict__ out)
{
    int bh = blockIdx.x;
    int h = bh % 96, d = (bh / 96) % 6, b = bh / 576;
    __shared__ u16 tile[96][152];
    __shared__ float stat[96][2];
    const u16* src = gsrc + (size_t)bh * 96 * 144;
    for (int i = threadIdx.x; i < 1728; i += 256) {
        int wt = i / 18, c8 = i - wt * 18;
        *(short8*)&tile[wt][c8 * 8] = *(const short8*)&src[wt * 144 + c8 * 8];
    }
    __syncthreads();
    if (threadIdx.x < 96) {
        const u32* row = (const u32*)&tile[threadIdx.x][0];
        float s = 0.f, s2 = 0.f;
        #pragma unroll
        for (int j = 0; j < 72; j++) {
            float lo, hi; unpack2(row[j], lo, hi);
            s += lo + hi; s2 += lo * lo + hi * hi;
        }
        float mu = s * (1.f / 144.f);
        float var = s2 * (1.f / 144.f) - mu * mu;
        stat[threadIdx.x][0] = mu;
        stat[threadIdx.x][1] = rsqrtf(fmaxf(var, 0.f) + 1e-5f);
    }
    __syncthreads();
    size_t obase = ((size_t)(b * 6 + d) * 144) * 9216 + h * 96;
    for (int i = threadIdx.x; i < 96 * 144; i += blockDim.x) {
        int c = i / 96, wt = i - c * 96;
        out[obase + (size_t)c * 9216 + wt] =
            (bf2f(tile[wt][c]) - stat[wt][0]) * stat[wt][1] * g[c] + bt[c];
    }
}

extern "C" void kernel_launch(void* const* d_in, const int* in_sizes, int n_in,
                              void* d_out, int out_size, void* d_ws, size_t ws_size,
                              hipStream_t stream) {
    const float* x     = (const float*)d_in[0];
    const float* convw = (const float*)d_in[1];
    const float* convb = (const float*)d_in[2];
    const float* ln0g  = (const float*)d_in[3];
    const float* ln0b  = (const float*)d_in[4];
    const float* n1g   = (const float*)d_in[5];
    const float* n1b   = (const float*)d_in[6];
    const float* qkvw  = (const float*)d_in[7];
    const float* qkvb  = (const float*)d_in[8];
    const float* rpb   = (const float*)d_in[9];
    const float* projw = (const float*)d_in[10];
    const float* projb = (const float*)d_in[11];
    const float* n2g   = (const float*)d_in[12];
    const float* n2b   = (const float*)d_in[13];
    const float* fc1w  = (const float*)d_in[14];
    const float* fc1b  = (const float*)d_in[15];
    const float* fc2w  = (const float*)d_in[16];
    const float* fc2b  = (const float*)d_in[17];
    const float* linw  = (const float*)d_in[18];
    const float* linb  = (const float*)d_in[19];
    const float* ln1g  = (const float*)d_in[20];
    const float* ln1b  = (const float*)d_in[21];

    // ws layout: f fp32 | tok bf16 | wbuf | bexp | qkvbuf (rest; sized by ws_size)
    char* wp = (char*)d_ws;
    float* f    = (float*)wp;             wp += (size_t)TS * 4;
    u16*   tok  = (u16*)wp;               wp += (size_t)TS * 2;
    u16*   wbuf = (u16*)wp;               wp += 352512ull * 2;
    float* bexp = (float*)wp;             wp += 196608ull * 4;
    u16*   qkvbuf = (u16*)wp;
    size_t rest = ws_size - (size_t)(wp - (char*)d_ws);
    int nch = (rest >= (size_t)NTOK * 432 * 2) ? 1
            : (rest >= (size_t)NTOK * 216 * 2) ? 2 : 4;
    int nm  = (rest >= (size_t)NTOK * 288 * 2) ? 1
            : (rest >= (size_t)NTOK * 144 * 2) ? 2 : 3;
    float* y0 = (float*)d_out;   // conv+LN0 output parked in d_out until the end

    convert_weights<<<2145, 256, 0, stream>>>(qkvw, projw, fc1w, fc2w, linw, wbuf, rpb, bexp);
    conv_ln0_row<<<1152, 256, 0, stream>>>(x, convw, convb, ln0g, ln0b, y0);

    for (int layer = 0; layer < 2; ++layer) {
        const u16* qw  = wbuf + (size_t)layer * 62208;
        const u16* pw  = wbuf + 124416 + (size_t)layer * 20736;
        const u16* f1w = wbuf + 165888 + (size_t)layer * 41472;
        const u16* f2w = wbuf + 248832 + (size_t)layer * 41472;
        const float* qb  = qkvb + (size_t)layer * 432;
        const float* pb  = projb + (size_t)layer * 144;
        const float* g1  = n1g + layer * 144;
        const float* b1  = n1b + layer * 144;
        const float* g2  = n2g + layer * 144;
        const float* b2  = n2b + layer * 144;
        const float* f1b = fc1b + (size_t)layer * 288;
        const float* f2b = fc2b + (size_t)layer * 144;
        const float* bx  = bexp + (size_t)layer * 98304;

        // attention in nch token chunks; LN1 + roll + window-gather fused into qkv A-staging
        // (AMODE 6); attn output overwrites its chunk's tok region in head-major layout
        const float* asrc = (layer == 0) ? y0 : f;
        int chtok = NTOK / nch, chwin = NWIN / nch;
        for (int c = 0; c < nch; c++) {
            if (layer == 0)
                mgemm<6, 6, 0, 1, 1><<<dim3(3, chtok / 64), 192, 0, stream>>>(
                    asrc, qw, qb, qkvbuf, nullptr, nullptr, g1, b1,
                    c * chtok, 144, 144, chtok, 0);
            else
                mgemm<6, 6, 1, 1, 1><<<dim3(3, chtok / 64), 192, 0, stream>>>(
                    asrc, qw, qb, qkvbuf, nullptr, nullptr, g1, b1,
                    c * chtok, 144, 144, chtok, 0);
            u16* ob = tok + (size_t)c * chtok * 144;
            if (layer == 0)
                attn_mfma<0><<<dim3(chwin, 6), 256, 0, stream>>>(qkvbuf, bx, ob, c * chwin, chtok);
            else
                attn_mfma<1><<<dim3(chwin, 6), 256, 0, stream>>>(qkvbuf, bx, ob, c * chwin, chtok);
        }

        // proj (AMODE 3: chunked head-major A) + window-reverse scatter into f
        if (layer == 0)
            mgemm<3, 5, 0, 1, 1><<<dim3(1, NTOK / 64), 192, 0, stream>>>(
                tok, pw, pb, nullptr, f, y0, nullptr, nullptr, 0, chtok, 144, 144, 0);
        else
            mgemm<3, 2, 1, 1, 1><<<dim3(1, NTOK / 64), 192, 0, stream>>>(
                tok, pw, pb, nullptr, f, nullptr, nullptr, nullptr, 0, chtok, 144, 144, 0);

        // MLP in nm chunks (hidden lives in qkvbuf: fcch x 288 bf16)
        // LN2 fused into fc1's A-staging (AMODE 5, reads f fp32 directly)
        int fcch = NTOK / nm;
        for (int c = 0; c < nm; c++) {
            int mst = c * fcch;
            mgemm<5, 1, 0, 1, 1><<<dim3(2, fcch / 64), 192, 0, stream>>>(
                f, f1w, f1b, qkvbuf, nullptr, nullptr, g2, b2, mst, 144, 144, 288, 0);
            mgemm<2, 3, 0, 1, 2><<<dim3(1, fcch / 64), 192, 0, stream>>>(
                qkvbuf, f2w, f2b, nullptr, f, nullptr, nullptr, nullptr, 0, 288, 288, 144, mst);
        }
    }

    // final linear + conv-residual y0 -> tok (bf16, spatial rows)
    mgemm<0, 4, 0, 1, 1><<<dim3(1, NTOK / 64), 192, 0, stream>>>(
        f, wbuf + 331776, linb, tok, nullptr, y0, nullptr, nullptr, 0, 144, 144, 144, 0);

    // trailing LN + transpose to (n, d, c, h, w), fp32 out
    final_ln_out_kernel<<<2 * 6 * 96, 256, 0, stream>>>(tok, ln1g, ln1b, (float*)d_out);
}